// Round 7
// baseline (1032.601 us; speedup 1.0000x reference)
//
#include <hip/hip_runtime.h>
#include <hip/hip_bf16.h>
#include <math.h>

#define H 300
#define WAVE 64
#define STRB 320   // padded bf16 row stride (640 B; 40 chunks of 16 B)
#define NCH 40     // u16x8 chunks per row
#define NS 6       // edge streams per gather block
#define ACT 240    // NS*NCH active threads

typedef short bf16x8 __attribute__((ext_vector_type(8)));
typedef unsigned short u16;
typedef u16 u16x8 __attribute__((ext_vector_type(8)));
typedef u16 u16x4 __attribute__((ext_vector_type(4)));
typedef short short4v __attribute__((ext_vector_type(4)));
typedef float f32x4 __attribute__((ext_vector_type(4)));

__device__ inline unsigned short f2b(float f) {
    union { float f; unsigned int u; } x; x.f = f;
    unsigned int r = x.u + 0x7FFF + ((x.u >> 16) & 1);
    return (unsigned short)(r >> 16);
}
__device__ inline float b2f(u16 h) {
    union { float f; unsigned int u; } x; x.u = ((unsigned int)h) << 16;
    return x.f;
}

// ---------------------------------------------------------------------------
// l2 normalize rows: one wave per row; writes fp32 + padded bf16 mirror
// ---------------------------------------------------------------------------
__global__ void k_l2norm(const float* __restrict__ x, float* __restrict__ out,
                         u16* __restrict__ outb, int n) {
    int wave = blockIdx.x * (blockDim.x / WAVE) + (threadIdx.x >> 6);
    int lane = threadIdx.x & 63;
    if (wave >= n) return;
    const float* row = x + (long)wave * H;
    float s = 0.f;
    for (int j = lane; j < H; j += WAVE) { float v = row[j]; s += v * v; }
    for (int o = 32; o > 0; o >>= 1) s += __shfl_xor(s, o);
    float sc = 1.0f / fmaxf(sqrtf(s), 1e-12f);
    float* orow = out + (long)wave * H;
    u16* brow = outb + (long)wave * STRB;
    for (int j = lane; j < H; j += WAVE) {
        float v = row[j] * sc;
        orow[j] = v;
        brow[j] = f2b(v);
    }
    for (int j = H + lane; j < STRB; j += WAVE) brow[j] = 0;
}

__global__ void k_zero_int(int* p, int n) {
    int i = blockIdx.x * blockDim.x + threadIdx.x;
    int stride = gridDim.x * blockDim.x;
    for (; i < n; i += stride) p[i] = 0;
}

__global__ void k_count_deg(const int* __restrict__ ei_i, int* __restrict__ deg, int E) {
    int i = blockIdx.x * blockDim.x + threadIdx.x;
    int stride = gridDim.x * blockDim.x;
    for (; i < E; i += stride) atomicAdd(&deg[ei_i[i]], 1);
}

__global__ void k_dinv(const int* __restrict__ deg, float* __restrict__ dinv, int n) {
    int i = blockIdx.x * blockDim.x + threadIdx.x;
    int stride = gridDim.x * blockDim.x;
    for (; i < n; i += stride) {
        int d = deg[i];
        dinv[i] = (d > 0) ? 1.0f / sqrtf((float)d) : 0.0f;
    }
}

__global__ void k_scan(const int* __restrict__ deg, int* __restrict__ offsets,
                       int* __restrict__ cursor, int n) {
    __shared__ int sh[1024];
    __shared__ int carry_sh;
    int tid = threadIdx.x;
    if (tid == 0) carry_sh = 0;
    __syncthreads();
    for (int base = 0; base < n; base += 1024) {
        int v = (base + tid < n) ? deg[base + tid] : 0;
        sh[tid] = v;
        __syncthreads();
        for (int off = 1; off < 1024; off <<= 1) {
            int add = (tid >= off) ? sh[tid - off] : 0;
            __syncthreads();
            sh[tid] += add;
            __syncthreads();
        }
        int total = sh[1023];
        int exc = sh[tid] - v;
        int carry = carry_sh;
        if (base + tid < n) {
            int o = carry + exc;
            offsets[base + tid] = o;
            cursor[base + tid] = o;
        }
        __syncthreads();
        if (tid == 0) carry_sh = carry + total;
        __syncthreads();
    }
    if (tid == 0) offsets[n] = carry_sh;
}

__global__ void k_fill_csr(const int* __restrict__ ei_j, const int* __restrict__ ei_i,
                           int* __restrict__ cursor, int* __restrict__ csr_src, int E) {
    int i = blockIdx.x * blockDim.x + threadIdx.x;
    int stride = gridDim.x * blockDim.x;
    for (; i < E; i += stride) {
        int dst = ei_i[i];
        int pos = atomicAdd(&cursor[dst], 1);
        csr_src[pos] = ei_j[i];
    }
}

// ---------------------------------------------------------------------------
// W fp32 [300][300] -> padded bf16 [320][320], pads zero
// ---------------------------------------------------------------------------
__global__ void k_conv_w(const float* __restrict__ W, u16* __restrict__ Wb) {
    int idx = blockIdx.x * blockDim.x + threadIdx.x;
    int stride = gridDim.x * blockDim.x;
    for (; idx < STRB * STRB; idx += stride) {
        int r = idx / STRB, c = idx - r * STRB;
        Wb[idx] = (r < H && c < H) ? f2b(W[r * H + c]) : 0;
    }
}

// ---------------------------------------------------------------------------
// MFMA NT GEMM, full-width blocks: BM=64 rows x BN=320 cols per block.
// 4 waves; wave w owns rows 0..63 x cols [w*80, w*80+80) = acc[4][5].
// X fetched exactly once (1-D grid); W is L2-resident.
// A input: Xb (bf16, stride STRB) if non-null, else Xf (fp32, stride H).
// mode A (outb != null): bf16 rows stride STRB (pads zeroed)
// mode B: highway epilogue, optional fp32 out + optional bf16 mirror
// ---------------------------------------------------------------------------
#define GBM 64
#define GBK 32
#define LDP 40

__global__ __launch_bounds__(256) void k_gemm_fused(
        const u16* __restrict__ Xb, const float* __restrict__ Xf,
        const u16* __restrict__ Wb,
        u16* __restrict__ outb,
        const float* __restrict__ hwbias,
        const float* __restrict__ xnew, const float* __restrict__ xold,
        float* __restrict__ outf, long ostride,
        u16* __restrict__ mirror,
        int n_rows) {
    __shared__ __align__(16) short As[GBM * LDP];
    __shared__ __align__(16) short Bs[STRB * LDP];
    const int tid = threadIdx.x;
    const int bm = blockIdx.x * GBM;
    const int lane = tid & 63;
    const int wid = tid >> 6;           // 0..3 -> col strip [wid*80, wid*80+80)
    const int lrow = lane & 15;
    const int kgrp = lane >> 4;

    f32x4 acc[4][5];
    #pragma unroll
    for (int m = 0; m < 4; m++)
        #pragma unroll
        for (int n = 0; n < 5; n++) acc[m][n] = (f32x4){0.f, 0.f, 0.f, 0.f};

    for (int k0 = 0; k0 < STRB; k0 += GBK) {
        if (Xb) {
            // bf16 staging: 64x32, 256 u16x8 chunks, 1/thread
            int r = tid >> 2, c = (tid & 3) << 3;
            int gr = bm + r;
            u16x8 v = {0, 0, 0, 0, 0, 0, 0, 0};
            if (gr < n_rows) v = *(const u16x8*)&Xb[(long)gr * STRB + k0 + c];
            *(u16x8*)&As[r * LDP + c] = v;
        } else {
            // fp32 staging with cvt: 64x32, 512 quads, 2/thread
            #pragma unroll
            for (int i = 0; i < 2; ++i) {
                int q = tid + i * 256;
                int r = q >> 3, c = (q & 7) << 2;
                int gr = bm + r, gk = k0 + c;
                float v0 = 0.f, v1 = 0.f, v2 = 0.f, v3 = 0.f;
                if (gr < n_rows && gk < H) {
                    const float* p = Xf + (long)gr * H + gk;
                    if (gk + 3 < H) {
                        float4 f = *(const float4*)p;
                        v0 = f.x; v1 = f.y; v2 = f.z; v3 = f.w;
                    } else {
                        v0 = p[0];
                        if (gk + 1 < H) v1 = p[1];
                        if (gk + 2 < H) v2 = p[2];
                    }
                }
                short4v h;
                h[0] = (short)f2b(v0); h[1] = (short)f2b(v1);
                h[2] = (short)f2b(v2); h[3] = (short)f2b(v3);
                *(short4v*)&As[r * LDP + c] = h;
            }
        }
        // W staging: 320x32 bf16, 1280 chunks, 5/thread
        #pragma unroll
        for (int i = 0; i < 5; ++i) {
            int q = tid + i * 256;
            int r = q >> 2, c = (q & 3) << 3;
            u16x8 v = *(const u16x8*)&Wb[(long)r * STRB + k0 + c];
            *(u16x8*)&Bs[r * LDP + c] = v;
        }
        __syncthreads();

        bf16x8 af[4], bfr[5];
        #pragma unroll
        for (int m = 0; m < 4; m++)
            af[m] = *(const bf16x8*)&As[(m * 16 + lrow) * LDP + kgrp * 8];
        #pragma unroll
        for (int n = 0; n < 5; n++)
            bfr[n] = *(const bf16x8*)&Bs[(wid * 80 + n * 16 + lrow) * LDP + kgrp * 8];
        #pragma unroll
        for (int m = 0; m < 4; m++)
            #pragma unroll
            for (int n = 0; n < 5; n++)
                acc[m][n] = __builtin_amdgcn_mfma_f32_16x16x32_bf16(af[m], bfr[n], acc[m][n], 0, 0, 0);
        __syncthreads();
    }

    if (outb) {
        #pragma unroll
        for (int m = 0; m < 4; m++)
            #pragma unroll
            for (int n = 0; n < 5; n++) {
                int gc = wid * 80 + n * 16 + lrow;
                #pragma unroll
                for (int r = 0; r < 4; r++) {
                    int gr = bm + m * 16 + kgrp * 4 + r;
                    if (gr < n_rows) outb[(long)gr * STRB + gc] = (gc < H) ? f2b(acc[m][n][r]) : 0;
                }
            }
    } else {
        #pragma unroll
        for (int m = 0; m < 4; m++)
            #pragma unroll
            for (int n = 0; n < 5; n++) {
                int gc = wid * 80 + n * 16 + lrow;
                bool colv = (gc < H);
                float bb = colv ? hwbias[gc] : 0.f;
                #pragma unroll
                for (int r = 0; r < 4; r++) {
                    int gr = bm + m * 16 + kgrp * 4 + r;
                    if (gr >= n_rows) continue;
                    if (colv) {
                        float pre = acc[m][n][r] + bb;
                        float g = 1.0f / (1.0f + __expf(-pre));
                        long off = (long)gr * H + gc;
                        float val = g * xnew[off] + (1.0f - g) * xold[off];
                        if (outf) outf[(long)gr * ostride + gc] = val;
                        if (mirror) mirror[(long)gr * STRB + gc] = f2b(val);
                    } else if (mirror) {
                        mirror[(long)gr * STRB + gc] = 0;
                    }
                }
            }
    }
}

// ---------------------------------------------------------------------------
// GCN gather from bf16 rows, 6 edge-streams x 40 chunks
// ---------------------------------------------------------------------------
__global__ __launch_bounds__(256) void k_gcn_gather_b(const u16* __restrict__ xb,
                                                      const float* __restrict__ dinv,
                                                      const int* __restrict__ offs,
                                                      const int* __restrict__ csr,
                                                      float* __restrict__ out) {
    int i = blockIdx.x;
    int t = threadIdx.x;
    int esub = t / NCH;
    int chunk = t - esub * NCH;
    bool active = (t < ACT);
    int start = offs[i], end = offs[i + 1];
    __shared__ float wsh[256];
    __shared__ int ssh[256];
    __shared__ float redbuf[NS * STRB];
    float accv[8] = {0.f, 0.f, 0.f, 0.f, 0.f, 0.f, 0.f, 0.f};
    float di = dinv[i];
    for (int cbase = start; cbase < end; cbase += 256) {
        int p = cbase + t;
        if (p < end) {
            int src = csr[p];
            ssh[t] = src;
            wsh[t] = di * dinv[src];
        }
        __syncthreads();
        int cnt = min(256, end - cbase);
        if (active) {
            for (int q = esub; q < cnt; q += NS) {
                float w = wsh[q];
                const u16* row = xb + (long)ssh[q] * STRB;
                u16x8 v = *(const u16x8*)&row[chunk * 8];
                #pragma unroll
                for (int j = 0; j < 8; j++) accv[j] += w * b2f(v[j]);
            }
        }
        __syncthreads();
    }
    if (active) {
        #pragma unroll
        for (int j = 0; j < 8; j++) redbuf[esub * STRB + chunk * 8 + j] = accv[j];
    }
    __syncthreads();
    for (int c = t; c < H; c += 256) {
        float s = redbuf[c] + redbuf[STRB + c] + redbuf[2 * STRB + c]
                + redbuf[3 * STRB + c] + redbuf[4 * STRB + c] + redbuf[5 * STRB + c];
        out[(long)i * H + c] = fmaxf(s, 0.f);
    }
}

// ---------------------------------------------------------------------------
// dual dot from bf16 mirror: one wave per row
// ---------------------------------------------------------------------------
__global__ void k_dual_dot_b(const u16* __restrict__ xb,
                             const float* __restrict__ ai, const float* __restrict__ aj,
                             float* __restrict__ s_i, float* __restrict__ s_j, int n) {
    int wave = blockIdx.x * (blockDim.x / WAVE) + (threadIdx.x >> 6);
    int lane = threadIdx.x & 63;
    if (wave >= n) return;
    const u16* row = xb + (long)wave * STRB;
    float d0 = 0.f, d1 = 0.f;
    {
        u16x4 v = *(const u16x4*)&row[lane * 4];
        float4 a4 = *(const float4*)&ai[lane * 4];
        float4 j4 = *(const float4*)&aj[lane * 4];
        float x0 = b2f(v[0]), x1 = b2f(v[1]), x2 = b2f(v[2]), x3 = b2f(v[3]);
        d0 = x0 * a4.x + x1 * a4.y + x2 * a4.z + x3 * a4.w;
        d1 = x0 * j4.x + x1 * j4.y + x2 * j4.z + x3 * j4.w;
    }
    if (lane < 11) {  // cols 256..299 (44 elems = 11 lanes x 4)
        u16x4 v = *(const u16x4*)&row[256 + lane * 4];
        float4 a4 = *(const float4*)&ai[256 + lane * 4];
        float4 j4 = *(const float4*)&aj[256 + lane * 4];
        float x0 = b2f(v[0]), x1 = b2f(v[1]), x2 = b2f(v[2]), x3 = b2f(v[3]);
        d0 += x0 * a4.x + x1 * a4.y + x2 * a4.z + x3 * a4.w;
        d1 += x0 * j4.x + x1 * j4.y + x2 * j4.z + x3 * j4.w;
    }
    for (int o = 32; o > 0; o >>= 1) { d0 += __shfl_down(d0, o); d1 += __shfl_down(d1, o); }
    if (lane == 0) { s_i[wave] = d0; s_j[wave] = d1; }
}

// ---------------------------------------------------------------------------
// GAT gather from bf16 rows with fused segment-softmax, 6 streams x 40 chunks
// ---------------------------------------------------------------------------
__global__ __launch_bounds__(256) void k_gat_gather_b(const u16* __restrict__ xb,
                                                      const float* __restrict__ s_i_arr,
                                                      const float* __restrict__ s_j_arr,
                                                      const int* __restrict__ offs,
                                                      const int* __restrict__ csr,
                                                      float* __restrict__ out, long out_stride,
                                                      int out_off) {
    int i = blockIdx.x;
    int t = threadIdx.x;
    int esub = t / NCH;
    int chunk = t - esub * NCH;
    bool active = (t < ACT);
    int start = offs[i], end = offs[i + 1];
    int deg = end - start;
    __shared__ float wsh[256];
    __shared__ int ssh[256];
    __shared__ float redm[256];
    __shared__ float reds[256];
    __shared__ float redbuf[NS * STRB];
    float accv[8] = {0.f, 0.f, 0.f, 0.f, 0.f, 0.f, 0.f, 0.f};

    if (deg > 0) {
        float si = s_i_arr[i];
        if (deg <= 64) {
            if (t < 64) {
                float sc = 0.f;
                if (t < deg) {
                    int src = csr[start + t];
                    ssh[t] = src;
                    sc = si + s_j_arr[src];
                    sc = (sc >= 0.f) ? sc : 0.01f * sc;
                }
                float mm = (t < deg) ? sc : -1e30f;
                for (int o = 32; o > 0; o >>= 1) mm = fmaxf(mm, __shfl_xor(mm, o));
                float ex = (t < deg) ? __expf(sc - mm) : 0.f;
                float ss = ex;
                for (int o = 32; o > 0; o >>= 1) ss += __shfl_xor(ss, o);
                if (t < deg) wsh[t] = ex / (ss + 1e-16f);
            }
            __syncthreads();
            if (active) {
                for (int q = esub; q < deg; q += NS) {
                    float w = wsh[q];
                    const u16* row = xb + (long)ssh[q] * STRB;
                    u16x8 v = *(const u16x8*)&row[chunk * 8];
                    #pragma unroll
                    for (int j = 0; j < 8; j++) accv[j] += w * b2f(v[j]);
                }
            }
        } else if (deg <= 256) {
            float sc = 0.f;
            float m_t = -1e30f, s_t = 0.f;
            if (t < deg) {
                int src = csr[start + t];
                sc = si + s_j_arr[src];
                sc = (sc >= 0.f) ? sc : 0.01f * sc;
                m_t = sc; s_t = 1.0f;
                ssh[t] = src;
            }
            redm[t] = m_t; reds[t] = s_t;
            __syncthreads();
            for (int o = 128; o > 0; o >>= 1) {
                if (t < o) {
                    float m1 = redm[t], m2 = redm[t + o];
                    float mm = fmaxf(m1, m2);
                    reds[t] = reds[t] * __expf(m1 - mm) + reds[t + o] * __expf(m2 - mm);
                    redm[t] = mm;
                }
                __syncthreads();
            }
            float m = redm[0];
            float inv = 1.0f / (reds[0] + 1e-16f);
            if (t < deg) wsh[t] = __expf(sc - m) * inv;
            __syncthreads();
            if (active) {
                for (int q = esub; q < deg; q += NS) {
                    float w = wsh[q];
                    const u16* row = xb + (long)ssh[q] * STRB;
                    u16x8 v = *(const u16x8*)&row[chunk * 8];
                    #pragma unroll
                    for (int j = 0; j < 8; j++) accv[j] += w * b2f(v[j]);
                }
            }
        } else {
            float m_t = -1e30f, s_t = 0.f;
            for (int p = start + t; p < end; p += 256) {
                float sc = si + s_j_arr[csr[p]];
                sc = (sc >= 0.f) ? sc : 0.01f * sc;
                if (sc > m_t) { s_t = s_t * __expf(m_t - sc) + 1.0f; m_t = sc; }
                else s_t += __expf(sc - m_t);
            }
            redm[t] = m_t; reds[t] = s_t;
            __syncthreads();
            for (int o = 128; o > 0; o >>= 1) {
                if (t < o) {
                    float m1 = redm[t], m2 = redm[t + o];
                    float mm = fmaxf(m1, m2);
                    reds[t] = reds[t] * __expf(m1 - mm) + reds[t + o] * __expf(m2 - mm);
                    redm[t] = mm;
                }
                __syncthreads();
            }
            float m = redm[0];
            float inv = 1.0f / (reds[0] + 1e-16f);
            __syncthreads();
            for (int cbase = start; cbase < end; cbase += 256) {
                int p = cbase + t;
                if (p < end) {
                    int src = csr[p];
                    float sc = si + s_j_arr[src];
                    sc = (sc >= 0.f) ? sc : 0.01f * sc;
                    ssh[t] = src;
                    wsh[t] = __expf(sc - m) * inv;
                }
                __syncthreads();
                int cnt = min(256, end - cbase);
                if (active) {
                    for (int q = esub; q < cnt; q += NS) {
                        float w = wsh[q];
                        const u16* row = xb + (long)ssh[q] * STRB;
                        u16x8 v = *(const u16x8*)&row[chunk * 8];
                        #pragma unroll
                        for (int j = 0; j < 8; j++) accv[j] += w * b2f(v[j]);
                    }
                }
                __syncthreads();
            }
        }
    }
    if (active) {
        #pragma unroll
        for (int j = 0; j < 8; j++) redbuf[esub * STRB + chunk * 8 + j] = accv[j];
    }
    __syncthreads();
    for (int c = t; c < H; c += 256) {
        float s = redbuf[c] + redbuf[STRB + c] + redbuf[2 * STRB + c]
                + redbuf[3 * STRB + c] + redbuf[4 * STRB + c] + redbuf[5 * STRB + c];
        out[(long)i * out_stride + out_off + c] = fmaxf(s, 0.f);
    }
}

// ---------------------------------------------------------------------------
// launch
// ---------------------------------------------------------------------------
extern "C" void kernel_launch(void* const* d_in, const int* in_sizes, int n_in,
                              void* d_out, int out_size, void* d_ws, size_t ws_size,
                              hipStream_t stream) {
    const float* x_e     = (const float*)d_in[0];
    const int*   ei_all  = (const int*)d_in[3];
    const float* gcn1_W  = (const float*)d_in[5];
    const float* hw1_W   = (const float*)d_in[6];
    const float* hw1_b   = (const float*)d_in[7];
    const float* gat1_ai = (const float*)d_in[8];
    const float* gat1_aj = (const float*)d_in[9];
    const float* ghw1_W  = (const float*)d_in[10];
    const float* ghw1_b  = (const float*)d_in[11];
    const float* gat2_ai = (const float*)d_in[12];
    const float* gat2_aj = (const float*)d_in[13];
    const float* ghw2_W  = (const float*)d_in[14];
    const float* ghw2_b  = (const float*)d_in[15];
    const float* gat_ai  = (const float*)d_in[16];
    const float* gat_aj  = (const float*)d_in[17];

    const int N = in_sizes[0] / H;
    const int E = in_sizes[3] / 2;
    const int* ei_j = ei_all;
    const int* ei_i = ei_all + E;

    float* out = (float*)d_out;

    size_t NH = (size_t)N * H;
    float* A      = (float*)d_ws;
    float* B      = A + NH;
    float* C      = B + NH;
    float* sbi    = C + NH;
    float* sbj    = sbi + N;
    float* dinv   = sbj + N;
    int*   deg    = (int*)(dinv + N);
    int*   offs   = deg + N;
    int*   cursor = offs + (N + 1);
    int*   csr    = cursor + N;             // E ints
    u16*   wb0    = (u16*)(csr + E);        // 4 x 320x320 bf16 weights
    u16*   wb1    = wb0 + STRB * STRB;
    u16*   wb2    = wb1 + STRB * STRB;
    u16*   wb3    = wb2 + STRB * STRB;

    // bf16 mirrors:
    //  x2b  at d_out[0:32MB)        written step5, last read step8 GEMM (step11 GEMM uses C fp32)
    //  x0b  at d_out+60MB           written step1, last read step5 GEMM
    //  x3b  at d_out+60MB           written step8, last read step10 gather
    //  xeb  in A (u16 view)         written step11 (A dead after step5), read steps 12-13
    //  hb   in B (u16 view)         steps 3-4
    u16* x2b = (u16*)d_out;
    u16* x0b = (u16*)(out + (size_t)15000000);   // 60 MB offset
    u16* x3b = x0b;
    u16* xeb = (u16*)A;
    u16* hb  = (u16*)B;

    dim3 blk256(256);
    int rowsPerBlock = 256 / WAVE;
    dim3 gridRows((N + rowsPerBlock - 1) / rowsPerBlock);
    dim3 gridNode(N);
    dim3 gridE(2048);
    dim3 gridW(100);
    dim3 gridGemm((N + GBM - 1) / GBM);

    // 1. x0 = l2_normalize(x_e) -> A (fp32) + x0b (bf16)
    hipLaunchKernelGGL(k_l2norm, gridRows, blk256, 0, stream, x_e, A, x0b, N);

    // 2. CSR build + weight conversion
    hipLaunchKernelGGL(k_zero_int, dim3(256), blk256, 0, stream, deg, N);
    hipLaunchKernelGGL(k_count_deg, gridE, blk256, 0, stream, ei_i, deg, E);
    hipLaunchKernelGGL(k_dinv, dim3(256), blk256, 0, stream, deg, dinv, N);
    hipLaunchKernelGGL(k_scan, dim3(1), dim3(1024), 0, stream, deg, offs, cursor, N);
    hipLaunchKernelGGL(k_fill_csr, gridE, blk256, 0, stream, ei_j, ei_i, cursor, csr, E);
    hipLaunchKernelGGL(k_conv_w, gridW, blk256, 0, stream, gcn1_W, wb0);
    hipLaunchKernelGGL(k_conv_w, gridW, blk256, 0, stream, hw1_W, wb1);
    hipLaunchKernelGGL(k_conv_w, gridW, blk256, 0, stream, ghw1_W, wb2);
    hipLaunchKernelGGL(k_conv_w, gridW, blk256, 0, stream, ghw2_W, wb3);

    // 3. hb = bf16(x0 @ gcn1_W.T) -> B (bf16)
    hipLaunchKernelGGL(k_gemm_fused, gridGemm, blk256, 0, stream,
                       x0b, (const float*)nullptr, wb0, hb,
                       (const float*)nullptr, (const float*)nullptr, (const float*)nullptr,
                       (float*)nullptr, (long)0, (u16*)nullptr, N);

    // 4. gcn_out -> C
    hipLaunchKernelGGL(k_gcn_gather_b, gridNode, blk256, 0, stream, hb, dinv, offs, csr, C);

    // 5. x2 = hw(x0, gcn_out) fused: pre = x0@hw1_W.T; out C fp32 + mirror x2b
    hipLaunchKernelGGL(k_gemm_fused, gridGemm, blk256, 0, stream,
                       x0b, (const float*)nullptr, wb1, (u16*)nullptr,
                       hw1_b, C, A, C, (long)H, x2b, N);

    // 6. dots for GAT1 from x2b
    hipLaunchKernelGGL(k_dual_dot_b, gridRows, blk256, 0, stream, x2b, gat1_ai, gat1_aj, sbi, sbj, N);

    // 7. GAT1 gather on x2b -> B
    hipLaunchKernelGGL(k_gat_gather_b, gridNode, blk256, 0, stream, x2b, sbi, sbj, offs, csr, B, (long)H, 0);

    // 8. x3 = hw(x2, gat1_out) fused: pre = x2b@ghw1_W.T; mirror x3b only (no fp32)
    hipLaunchKernelGGL(k_gemm_fused, gridGemm, blk256, 0, stream,
                       x2b, (const float*)nullptr, wb2, (u16*)nullptr,
                       ghw1_b, B, C, (float*)nullptr, (long)0, x3b, N);

    // 9. dots for GAT2 from x3b
    hipLaunchKernelGGL(k_dual_dot_b, gridRows, blk256, 0, stream, x3b, gat2_ai, gat2_aj, sbi, sbj, N);

    // 10. GAT2 gather on x3b -> B
    hipLaunchKernelGGL(k_gat_gather_b, gridNode, blk256, 0, stream, x3b, sbi, sbj, offs, csr, B, (long)H, 0);

    // 11. xe = hw(x2, gat2_out) fused: pre = C(fp32)@ghw2_W.T; out d_out[:,0:300] + mirror xeb(A)
    hipLaunchKernelGGL(k_gemm_fused, gridGemm, blk256, 0, stream,
                       (const u16*)nullptr, C, wb3, (u16*)nullptr,
                       ghw2_b, B, C, out, (long)(2 * H), xeb, N);

    // 12. dots for final GAT from xeb
    hipLaunchKernelGGL(k_dual_dot_b, gridRows, blk256, 0, stream, xeb, gat_ai, gat_aj, sbi, sbj, N);

    // 13. final GAT gather on xeb -> d_out[:,300:600]
    hipLaunchKernelGGL(k_gat_gather_b, gridNode, blk256, 0, stream, xeb, sbi, sbj, offs, csr, out, (long)(2 * H), H);
}

// Round 8
// 904.545 us; speedup vs baseline: 1.1416x; 1.1416x over previous
//
#include <hip/hip_runtime.h>
#include <hip/hip_bf16.h>
#include <math.h>

#define H 300
#define WAVE 64
#define STRB 320   // padded bf16 row stride (640 B; 40 chunks of 16 B)
#define NCH 40     // u16x8 chunks per row
#define NS 6       // edge streams per gather block
#define ACT 240    // NS*NCH active threads

typedef short bf16x8 __attribute__((ext_vector_type(8)));
typedef unsigned short u16;
typedef u16 u16x8 __attribute__((ext_vector_type(8)));
typedef u16 u16x4 __attribute__((ext_vector_type(4)));
typedef short short4v __attribute__((ext_vector_type(4)));
typedef float f32x4 __attribute__((ext_vector_type(4)));

__device__ inline unsigned short f2b(float f) {
    union { float f; unsigned int u; } x; x.f = f;
    unsigned int r = x.u + 0x7FFF + ((x.u >> 16) & 1);
    return (unsigned short)(r >> 16);
}
__device__ inline float b2f(u16 h) {
    union { float f; unsigned int u; } x; x.u = ((unsigned int)h) << 16;
    return x.f;
}

// ---------------------------------------------------------------------------
// l2 normalize rows: one wave per row; writes fp32 + padded bf16 mirror
// ---------------------------------------------------------------------------
__global__ void k_l2norm(const float* __restrict__ x, float* __restrict__ out,
                         u16* __restrict__ outb, int n) {
    int wave = blockIdx.x * (blockDim.x / WAVE) + (threadIdx.x >> 6);
    int lane = threadIdx.x & 63;
    if (wave >= n) return;
    const float* row = x + (long)wave * H;
    float s = 0.f;
    for (int j = lane; j < H; j += WAVE) { float v = row[j]; s += v * v; }
    for (int o = 32; o > 0; o >>= 1) s += __shfl_xor(s, o);
    float sc = 1.0f / fmaxf(sqrtf(s), 1e-12f);
    float* orow = out + (long)wave * H;
    u16* brow = outb + (long)wave * STRB;
    for (int j = lane; j < H; j += WAVE) {
        float v = row[j] * sc;
        orow[j] = v;
        brow[j] = f2b(v);
    }
    for (int j = H + lane; j < STRB; j += WAVE) brow[j] = 0;
}

__global__ void k_zero_int(int* p, int n) {
    int i = blockIdx.x * blockDim.x + threadIdx.x;
    int stride = gridDim.x * blockDim.x;
    for (; i < n; i += stride) p[i] = 0;
}

__global__ void k_count_deg(const int* __restrict__ ei_i, int* __restrict__ deg, int E) {
    int i = blockIdx.x * blockDim.x + threadIdx.x;
    int stride = gridDim.x * blockDim.x;
    for (; i < E; i += stride) atomicAdd(&deg[ei_i[i]], 1);
}

__global__ void k_dinv(const int* __restrict__ deg, float* __restrict__ dinv, int n) {
    int i = blockIdx.x * blockDim.x + threadIdx.x;
    int stride = gridDim.x * blockDim.x;
    for (; i < n; i += stride) {
        int d = deg[i];
        dinv[i] = (d > 0) ? 1.0f / sqrtf((float)d) : 0.0f;
    }
}

__global__ void k_scan(const int* __restrict__ deg, int* __restrict__ offsets,
                       int* __restrict__ cursor, int n) {
    __shared__ int sh[1024];
    __shared__ int carry_sh;
    int tid = threadIdx.x;
    if (tid == 0) carry_sh = 0;
    __syncthreads();
    for (int base = 0; base < n; base += 1024) {
        int v = (base + tid < n) ? deg[base + tid] : 0;
        sh[tid] = v;
        __syncthreads();
        for (int off = 1; off < 1024; off <<= 1) {
            int add = (tid >= off) ? sh[tid - off] : 0;
            __syncthreads();
            sh[tid] += add;
            __syncthreads();
        }
        int total = sh[1023];
        int exc = sh[tid] - v;
        int carry = carry_sh;
        if (base + tid < n) {
            int o = carry + exc;
            offsets[base + tid] = o;
            cursor[base + tid] = o;
        }
        __syncthreads();
        if (tid == 0) carry_sh = carry + total;
        __syncthreads();
    }
    if (tid == 0) offsets[n] = carry_sh;
}

__global__ void k_fill_csr(const int* __restrict__ ei_j, const int* __restrict__ ei_i,
                           int* __restrict__ cursor, int* __restrict__ csr_src, int E) {
    int i = blockIdx.x * blockDim.x + threadIdx.x;
    int stride = gridDim.x * blockDim.x;
    for (; i < E; i += stride) {
        int dst = ei_i[i];
        int pos = atomicAdd(&cursor[dst], 1);
        csr_src[pos] = ei_j[i];
    }
}

// ---------------------------------------------------------------------------
// W fp32 [300][300] -> padded bf16 [320][320], pads zero
// ---------------------------------------------------------------------------
__global__ void k_conv_w(const float* __restrict__ W, u16* __restrict__ Wb) {
    int idx = blockIdx.x * blockDim.x + threadIdx.x;
    int stride = gridDim.x * blockDim.x;
    for (; idx < STRB * STRB; idx += stride) {
        int r = idx / STRB, c = idx - r * STRB;
        Wb[idx] = (r < H && c < H) ? f2b(W[r * H + c]) : 0;
    }
}

// ---------------------------------------------------------------------------
// MFMA NT GEMM, BM=128 x BN=64, flattened 1-D grid with bn-fast work order
// and bijective XCD swizzle: the 5 column-blocks sharing an X panel run
// back-to-back on the same XCD -> X HBM-fetched once, L2-hit 4x.
// A input: Xb (bf16, stride STRB) if non-null, else Xf (fp32, stride H).
// mode A (outb != null): bf16 rows stride STRB (pads zeroed)
// mode B: highway epilogue, optional fp32 out + optional bf16 mirror
// ---------------------------------------------------------------------------
#define BM 128
#define BN 64
#define BK 32
#define LDP 40
#define NXCD 8

__global__ __launch_bounds__(256) void k_gemm_fused(
        const u16* __restrict__ Xb, const float* __restrict__ Xf,
        const u16* __restrict__ Wb,
        u16* __restrict__ outb,
        const float* __restrict__ hwbias,
        const float* __restrict__ xnew, const float* __restrict__ xold,
        float* __restrict__ outf, long ostride,
        u16* __restrict__ mirror,
        int n_rows) {
    __shared__ __align__(16) short As[BM * LDP];
    __shared__ __align__(16) short Bs[BN * LDP];
    const int tid = threadIdx.x;

    // bijective XCD swizzle (nwg may not be divisible by 8)
    const int nwg = gridDim.x;
    const int q = nwg / NXCD, r = nwg % NXCD;
    const int xcd = blockIdx.x % NXCD, idx = blockIdx.x / NXCD;
    const int wgid = (xcd < r ? xcd * (q + 1) : r * (q + 1) + (xcd - r) * q) + idx;
    const int bm = (wgid / 5) * BM;
    const int bn = (wgid % 5) * BN;

    const int lane = tid & 63;
    const int wid = tid >> 6;
    const int wr = wid >> 1;
    const int wc = wid & 1;
    const int lrow = lane & 15;
    const int kgrp = lane >> 4;

    f32x4 acc[4][2];
    #pragma unroll
    for (int m = 0; m < 4; m++)
        #pragma unroll
        for (int n = 0; n < 2; n++) acc[m][n] = (f32x4){0.f, 0.f, 0.f, 0.f};

    for (int k0 = 0; k0 < STRB; k0 += BK) {
        if (Xb) {
            // bf16 staging: 128x32, 512 u16x8 chunks, 2/thread
            #pragma unroll
            for (int i = 0; i < 2; ++i) {
                int qq = tid + i * 256;
                int rr = qq >> 2, c = (qq & 3) << 3;
                int gr = bm + rr;
                u16x8 v = {0, 0, 0, 0, 0, 0, 0, 0};
                if (gr < n_rows) v = *(const u16x8*)&Xb[(long)gr * STRB + k0 + c];
                *(u16x8*)&As[rr * LDP + c] = v;
            }
        } else {
            // fp32 staging with cvt: 128x32, 1024 quads, 4/thread
            #pragma unroll
            for (int i = 0; i < 4; ++i) {
                int qq = tid + i * 256;
                int rr = qq >> 3, c = (qq & 7) << 2;
                int gr = bm + rr, gk = k0 + c;
                float v0 = 0.f, v1 = 0.f, v2 = 0.f, v3 = 0.f;
                if (gr < n_rows && gk < H) {
                    const float* p = Xf + (long)gr * H + gk;
                    if (gk + 3 < H) {
                        float4 f = *(const float4*)p;
                        v0 = f.x; v1 = f.y; v2 = f.z; v3 = f.w;
                    } else {
                        v0 = p[0];
                        if (gk + 1 < H) v1 = p[1];
                        if (gk + 2 < H) v2 = p[2];
                    }
                }
                short4v h;
                h[0] = (short)f2b(v0); h[1] = (short)f2b(v1);
                h[2] = (short)f2b(v2); h[3] = (short)f2b(v3);
                *(short4v*)&As[rr * LDP + c] = h;
            }
        }
        // W staging: 64x32 bf16, 256 chunks, 1/thread
        {
            int rr = tid >> 2, c = (tid & 3) << 3;
            u16x8 v = *(const u16x8*)&Wb[(long)(bn + rr) * STRB + k0 + c];
            *(u16x8*)&Bs[rr * LDP + c] = v;
        }
        __syncthreads();

        bf16x8 af[4], bfr[2];
        #pragma unroll
        for (int m = 0; m < 4; m++) {
            int row = wr * 64 + m * 16 + lrow;
            af[m] = *(const bf16x8*)&As[row * LDP + kgrp * 8];
        }
        #pragma unroll
        for (int n = 0; n < 2; n++) {
            int col = wc * 32 + n * 16 + lrow;
            bfr[n] = *(const bf16x8*)&Bs[col * LDP + kgrp * 8];
        }
        #pragma unroll
        for (int m = 0; m < 4; m++)
            #pragma unroll
            for (int n = 0; n < 2; n++)
                acc[m][n] = __builtin_amdgcn_mfma_f32_16x16x32_bf16(af[m], bfr[n], acc[m][n], 0, 0, 0);
        __syncthreads();
    }

    if (outb) {
        #pragma unroll
        for (int m = 0; m < 4; m++)
            #pragma unroll
            for (int n = 0; n < 2; n++) {
                int gc = bn + wc * 32 + n * 16 + lrow;
                if (gc >= STRB) continue;
                #pragma unroll
                for (int rr = 0; rr < 4; rr++) {
                    int gr = bm + wr * 64 + m * 16 + kgrp * 4 + rr;
                    if (gr < n_rows) outb[(long)gr * STRB + gc] = (gc < H) ? f2b(acc[m][n][rr]) : 0;
                }
            }
    } else {
        #pragma unroll
        for (int m = 0; m < 4; m++)
            #pragma unroll
            for (int n = 0; n < 2; n++) {
                int gc = bn + wc * 32 + n * 16 + lrow;
                if (gc >= STRB) continue;
                bool colv = (gc < H);
                float bb = colv ? hwbias[gc] : 0.f;
                #pragma unroll
                for (int rr = 0; rr < 4; rr++) {
                    int gr = bm + wr * 64 + m * 16 + kgrp * 4 + rr;
                    if (gr >= n_rows) continue;
                    if (colv) {
                        float pre = acc[m][n][rr] + bb;
                        float g = 1.0f / (1.0f + __expf(-pre));
                        long off = (long)gr * H + gc;
                        float val = g * xnew[off] + (1.0f - g) * xold[off];
                        if (outf) outf[(long)gr * ostride + gc] = val;
                        if (mirror) mirror[(long)gr * STRB + gc] = f2b(val);
                    } else if (mirror) {
                        mirror[(long)gr * STRB + gc] = 0;
                    }
                }
            }
    }
}

// ---------------------------------------------------------------------------
// GCN gather from bf16 rows, 6 edge-streams x 40 chunks
// ---------------------------------------------------------------------------
__global__ __launch_bounds__(256) void k_gcn_gather_b(const u16* __restrict__ xb,
                                                      const float* __restrict__ dinv,
                                                      const int* __restrict__ offs,
                                                      const int* __restrict__ csr,
                                                      float* __restrict__ out) {
    int i = blockIdx.x;
    int t = threadIdx.x;
    int esub = t / NCH;
    int chunk = t - esub * NCH;
    bool active = (t < ACT);
    int start = offs[i], end = offs[i + 1];
    __shared__ float wsh[256];
    __shared__ int ssh[256];
    __shared__ float redbuf[NS * STRB];
    float accv[8] = {0.f, 0.f, 0.f, 0.f, 0.f, 0.f, 0.f, 0.f};
    float di = dinv[i];
    for (int cbase = start; cbase < end; cbase += 256) {
        int p = cbase + t;
        if (p < end) {
            int src = csr[p];
            ssh[t] = src;
            wsh[t] = di * dinv[src];
        }
        __syncthreads();
        int cnt = min(256, end - cbase);
        if (active) {
            for (int q = esub; q < cnt; q += NS) {
                float w = wsh[q];
                const u16* row = xb + (long)ssh[q] * STRB;
                u16x8 v = *(const u16x8*)&row[chunk * 8];
                #pragma unroll
                for (int j = 0; j < 8; j++) accv[j] += w * b2f(v[j]);
            }
        }
        __syncthreads();
    }
    if (active) {
        #pragma unroll
        for (int j = 0; j < 8; j++) redbuf[esub * STRB + chunk * 8 + j] = accv[j];
    }
    __syncthreads();
    for (int c = t; c < H; c += 256) {
        float s = redbuf[c] + redbuf[STRB + c] + redbuf[2 * STRB + c]
                + redbuf[3 * STRB + c] + redbuf[4 * STRB + c] + redbuf[5 * STRB + c];
        out[(long)i * H + c] = fmaxf(s, 0.f);
    }
}

// ---------------------------------------------------------------------------
// dual dot from bf16 mirror: one wave per row
// ---------------------------------------------------------------------------
__global__ void k_dual_dot_b(const u16* __restrict__ xb,
                             const float* __restrict__ ai, const float* __restrict__ aj,
                             float* __restrict__ s_i, float* __restrict__ s_j, int n) {
    int wave = blockIdx.x * (blockDim.x / WAVE) + (threadIdx.x >> 6);
    int lane = threadIdx.x & 63;
    if (wave >= n) return;
    const u16* row = xb + (long)wave * STRB;
    float d0 = 0.f, d1 = 0.f;
    {
        u16x4 v = *(const u16x4*)&row[lane * 4];
        float4 a4 = *(const float4*)&ai[lane * 4];
        float4 j4 = *(const float4*)&aj[lane * 4];
        float x0 = b2f(v[0]), x1 = b2f(v[1]), x2 = b2f(v[2]), x3 = b2f(v[3]);
        d0 = x0 * a4.x + x1 * a4.y + x2 * a4.z + x3 * a4.w;
        d1 = x0 * j4.x + x1 * j4.y + x2 * j4.z + x3 * j4.w;
    }
    if (lane < 11) {  // cols 256..299 (44 elems = 11 lanes x 4)
        u16x4 v = *(const u16x4*)&row[256 + lane * 4];
        float4 a4 = *(const float4*)&ai[256 + lane * 4];
        float4 j4 = *(const float4*)&aj[256 + lane * 4];
        float x0 = b2f(v[0]), x1 = b2f(v[1]), x2 = b2f(v[2]), x3 = b2f(v[3]);
        d0 += x0 * a4.x + x1 * a4.y + x2 * a4.z + x3 * a4.w;
        d1 += x0 * j4.x + x1 * j4.y + x2 * j4.z + x3 * j4.w;
    }
    for (int o = 32; o > 0; o >>= 1) { d0 += __shfl_down(d0, o); d1 += __shfl_down(d1, o); }
    if (lane == 0) { s_i[wave] = d0; s_j[wave] = d1; }
}

// ---------------------------------------------------------------------------
// GAT gather from bf16 rows with fused segment-softmax, 6 streams x 40 chunks
// ---------------------------------------------------------------------------
__global__ __launch_bounds__(256) void k_gat_gather_b(const u16* __restrict__ xb,
                                                      const float* __restrict__ s_i_arr,
                                                      const float* __restrict__ s_j_arr,
                                                      const int* __restrict__ offs,
                                                      const int* __restrict__ csr,
                                                      float* __restrict__ out, long out_stride,
                                                      int out_off) {
    int i = blockIdx.x;
    int t = threadIdx.x;
    int esub = t / NCH;
    int chunk = t - esub * NCH;
    bool active = (t < ACT);
    int start = offs[i], end = offs[i + 1];
    int deg = end - start;
    __shared__ float wsh[256];
    __shared__ int ssh[256];
    __shared__ float redm[256];
    __shared__ float reds[256];
    __shared__ float redbuf[NS * STRB];
    float accv[8] = {0.f, 0.f, 0.f, 0.f, 0.f, 0.f, 0.f, 0.f};

    if (deg > 0) {
        float si = s_i_arr[i];
        if (deg <= 64) {
            if (t < 64) {
                float sc = 0.f;
                if (t < deg) {
                    int src = csr[start + t];
                    ssh[t] = src;
                    sc = si + s_j_arr[src];
                    sc = (sc >= 0.f) ? sc : 0.01f * sc;
                }
                float mm = (t < deg) ? sc : -1e30f;
                for (int o = 32; o > 0; o >>= 1) mm = fmaxf(mm, __shfl_xor(mm, o));
                float ex = (t < deg) ? __expf(sc - mm) : 0.f;
                float ss = ex;
                for (int o = 32; o > 0; o >>= 1) ss += __shfl_xor(ss, o);
                if (t < deg) wsh[t] = ex / (ss + 1e-16f);
            }
            __syncthreads();
            if (active) {
                for (int q = esub; q < deg; q += NS) {
                    float w = wsh[q];
                    const u16* row = xb + (long)ssh[q] * STRB;
                    u16x8 v = *(const u16x8*)&row[chunk * 8];
                    #pragma unroll
                    for (int j = 0; j < 8; j++) accv[j] += w * b2f(v[j]);
                }
            }
        } else if (deg <= 256) {
            float sc = 0.f;
            float m_t = -1e30f, s_t = 0.f;
            if (t < deg) {
                int src = csr[start + t];
                sc = si + s_j_arr[src];
                sc = (sc >= 0.f) ? sc : 0.01f * sc;
                m_t = sc; s_t = 1.0f;
                ssh[t] = src;
            }
            redm[t] = m_t; reds[t] = s_t;
            __syncthreads();
            for (int o = 128; o > 0; o >>= 1) {
                if (t < o) {
                    float m1 = redm[t], m2 = redm[t + o];
                    float mm = fmaxf(m1, m2);
                    reds[t] = reds[t] * __expf(m1 - mm) + reds[t + o] * __expf(m2 - mm);
                    redm[t] = mm;
                }
                __syncthreads();
            }
            float m = redm[0];
            float inv = 1.0f / (reds[0] + 1e-16f);
            if (t < deg) wsh[t] = __expf(sc - m) * inv;
            __syncthreads();
            if (active) {
                for (int q = esub; q < deg; q += NS) {
                    float w = wsh[q];
                    const u16* row = xb + (long)ssh[q] * STRB;
                    u16x8 v = *(const u16x8*)&row[chunk * 8];
                    #pragma unroll
                    for (int j = 0; j < 8; j++) accv[j] += w * b2f(v[j]);
                }
            }
        } else {
            float m_t = -1e30f, s_t = 0.f;
            for (int p = start + t; p < end; p += 256) {
                float sc = si + s_j_arr[csr[p]];
                sc = (sc >= 0.f) ? sc : 0.01f * sc;
                if (sc > m_t) { s_t = s_t * __expf(m_t - sc) + 1.0f; m_t = sc; }
                else s_t += __expf(sc - m_t);
            }
            redm[t] = m_t; reds[t] = s_t;
            __syncthreads();
            for (int o = 128; o > 0; o >>= 1) {
                if (t < o) {
                    float m1 = redm[t], m2 = redm[t + o];
                    float mm = fmaxf(m1, m2);
                    reds[t] = reds[t] * __expf(m1 - mm) + reds[t + o] * __expf(m2 - mm);
                    redm[t] = mm;
                }
                __syncthreads();
            }
            float m = redm[0];
            float inv = 1.0f / (reds[0] + 1e-16f);
            __syncthreads();
            for (int cbase = start; cbase < end; cbase += 256) {
                int p = cbase + t;
                if (p < end) {
                    int src = csr[p];
                    float sc = si + s_j_arr[src];
                    sc = (sc >= 0.f) ? sc : 0.01f * sc;
                    ssh[t] = src;
                    wsh[t] = __expf(sc - m) * inv;
                }
                __syncthreads();
                int cnt = min(256, end - cbase);
                if (active) {
                    for (int q = esub; q < cnt; q += NS) {
                        float w = wsh[q];
                        const u16* row = xb + (long)ssh[q] * STRB;
                        u16x8 v = *(const u16x8*)&row[chunk * 8];
                        #pragma unroll
                        for (int j = 0; j < 8; j++) accv[j] += w * b2f(v[j]);
                    }
                }
                __syncthreads();
            }
        }
    }
    if (active) {
        #pragma unroll
        for (int j = 0; j < 8; j++) redbuf[esub * STRB + chunk * 8 + j] = accv[j];
    }
    __syncthreads();
    for (int c = t; c < H; c += 256) {
        float s = redbuf[c] + redbuf[STRB + c] + redbuf[2 * STRB + c]
                + redbuf[3 * STRB + c] + redbuf[4 * STRB + c] + redbuf[5 * STRB + c];
        out[(long)i * out_stride + out_off + c] = fmaxf(s, 0.f);
    }
}

// ---------------------------------------------------------------------------
// launch
// ---------------------------------------------------------------------------
extern "C" void kernel_launch(void* const* d_in, const int* in_sizes, int n_in,
                              void* d_out, int out_size, void* d_ws, size_t ws_size,
                              hipStream_t stream) {
    const float* x_e     = (const float*)d_in[0];
    const int*   ei_all  = (const int*)d_in[3];
    const float* gcn1_W  = (const float*)d_in[5];
    const float* hw1_W   = (const float*)d_in[6];
    const float* hw1_b   = (const float*)d_in[7];
    const float* gat1_ai = (const float*)d_in[8];
    const float* gat1_aj = (const float*)d_in[9];
    const float* ghw1_W  = (const float*)d_in[10];
    const float* ghw1_b  = (const float*)d_in[11];
    const float* gat2_ai = (const float*)d_in[12];
    const float* gat2_aj = (const float*)d_in[13];
    const float* ghw2_W  = (const float*)d_in[14];
    const float* ghw2_b  = (const float*)d_in[15];
    const float* gat_ai  = (const float*)d_in[16];
    const float* gat_aj  = (const float*)d_in[17];

    const int N = in_sizes[0] / H;
    const int E = in_sizes[3] / 2;
    const int* ei_j = ei_all;
    const int* ei_i = ei_all + E;

    float* out = (float*)d_out;

    size_t NH = (size_t)N * H;
    float* A      = (float*)d_ws;
    float* B      = A + NH;
    float* C      = B + NH;
    float* sbi    = C + NH;
    float* sbj    = sbi + N;
    float* dinv   = sbj + N;
    int*   deg    = (int*)(dinv + N);
    int*   offs   = deg + N;
    int*   cursor = offs + (N + 1);
    int*   csr    = cursor + N;             // E ints
    u16*   wb0    = (u16*)(csr + E);        // 4 x 320x320 bf16 weights
    u16*   wb1    = wb0 + STRB * STRB;
    u16*   wb2    = wb1 + STRB * STRB;
    u16*   wb3    = wb2 + STRB * STRB;

    // bf16 mirrors:
    //  x2b  at d_out[0:32MB)        written step5, last read step8 GEMM (step11 GEMM uses C fp32)
    //  x0b  at d_out+60MB           written step1, last read step5 GEMM
    //  x3b  at d_out+60MB           written step8, last read step10 gather
    //  xeb  in A (u16 view)         written step11 (A dead after step5), read steps 12-13
    //  hb   in B (u16 view)         steps 3-4
    u16* x2b = (u16*)d_out;
    u16* x0b = (u16*)(out + (size_t)15000000);   // 60 MB offset
    u16* x3b = x0b;
    u16* xeb = (u16*)A;
    u16* hb  = (u16*)B;

    dim3 blk256(256);
    int rowsPerBlock = 256 / WAVE;
    dim3 gridRows((N + rowsPerBlock - 1) / rowsPerBlock);
    dim3 gridNode(N);
    dim3 gridE(2048);
    dim3 gridW(100);
    dim3 gridGemm(((N + BM - 1) / BM) * 5);

    // 1. x0 = l2_normalize(x_e) -> A (fp32) + x0b (bf16)
    hipLaunchKernelGGL(k_l2norm, gridRows, blk256, 0, stream, x_e, A, x0b, N);

    // 2. CSR build + weight conversion
    hipLaunchKernelGGL(k_zero_int, dim3(256), blk256, 0, stream, deg, N);
    hipLaunchKernelGGL(k_count_deg, gridE, blk256, 0, stream, ei_i, deg, E);
    hipLaunchKernelGGL(k_dinv, dim3(256), blk256, 0, stream, deg, dinv, N);
    hipLaunchKernelGGL(k_scan, dim3(1), dim3(1024), 0, stream, deg, offs, cursor, N);
    hipLaunchKernelGGL(k_fill_csr, gridE, blk256, 0, stream, ei_j, ei_i, cursor, csr, E);
    hipLaunchKernelGGL(k_conv_w, gridW, blk256, 0, stream, gcn1_W, wb0);
    hipLaunchKernelGGL(k_conv_w, gridW, blk256, 0, stream, hw1_W, wb1);
    hipLaunchKernelGGL(k_conv_w, gridW, blk256, 0, stream, ghw1_W, wb2);
    hipLaunchKernelGGL(k_conv_w, gridW, blk256, 0, stream, ghw2_W, wb3);

    // 3. hb = bf16(x0 @ gcn1_W.T) -> B (bf16)
    hipLaunchKernelGGL(k_gemm_fused, gridGemm, blk256, 0, stream,
                       x0b, (const float*)nullptr, wb0, hb,
                       (const float*)nullptr, (const float*)nullptr, (const float*)nullptr,
                       (float*)nullptr, (long)0, (u16*)nullptr, N);

    // 4. gcn_out -> C
    hipLaunchKernelGGL(k_gcn_gather_b, gridNode, blk256, 0, stream, hb, dinv, offs, csr, C);

    // 5. x2 = hw(x0, gcn_out) fused: pre = x0@hw1_W.T; out C fp32 + mirror x2b
    hipLaunchKernelGGL(k_gemm_fused, gridGemm, blk256, 0, stream,
                       x0b, (const float*)nullptr, wb1, (u16*)nullptr,
                       hw1_b, C, A, C, (long)H, x2b, N);

    // 6. dots for GAT1 from x2b
    hipLaunchKernelGGL(k_dual_dot_b, gridRows, blk256, 0, stream, x2b, gat1_ai, gat1_aj, sbi, sbj, N);

    // 7. GAT1 gather on x2b -> B
    hipLaunchKernelGGL(k_gat_gather_b, gridNode, blk256, 0, stream, x2b, sbi, sbj, offs, csr, B, (long)H, 0);

    // 8. x3 = hw(x2, gat1_out) fused: pre = x2b@ghw1_W.T; mirror x3b only (no fp32)
    hipLaunchKernelGGL(k_gemm_fused, gridGemm, blk256, 0, stream,
                       x2b, (const float*)nullptr, wb2, (u16*)nullptr,
                       ghw1_b, B, C, (float*)nullptr, (long)0, x3b, N);

    // 9. dots for GAT2 from x3b
    hipLaunchKernelGGL(k_dual_dot_b, gridRows, blk256, 0, stream, x3b, gat2_ai, gat2_aj, sbi, sbj, N);

    // 10. GAT2 gather on x3b -> B
    hipLaunchKernelGGL(k_gat_gather_b, gridNode, blk256, 0, stream, x3b, sbi, sbj, offs, csr, B, (long)H, 0);

    // 11. xe = hw(x2, gat2_out) fused: pre = C(fp32)@ghw2_W.T; out d_out[:,0:300] + mirror xeb(A)
    hipLaunchKernelGGL(k_gemm_fused, gridGemm, blk256, 0, stream,
                       (const u16*)nullptr, C, wb3, (u16*)nullptr,
                       ghw2_b, B, C, out, (long)(2 * H), xeb, N);

    // 12. dots for final GAT from xeb
    hipLaunchKernelGGL(k_dual_dot_b, gridRows, blk256, 0, stream, xeb, gat_ai, gat_aj, sbi, sbj, N);

    // 13. final GAT gather on xeb -> d_out[:,300:600]
    hipLaunchKernelGGL(k_gat_gather_b, gridNode, blk256, 0, stream, xeb, sbi, sbj, offs, csr, out, (long)(2 * H), H);
}

// Round 9
// 868.797 us; speedup vs baseline: 1.1885x; 1.0411x over previous
//
#include <hip/hip_runtime.h>
#include <hip/hip_bf16.h>
#include <math.h>

#define H 300
#define WAVE 64
#define STRB 320   // padded bf16 row stride (640 B; 40 chunks of 16 B)
#define NCH 40     // u16x8 chunks per row
#define NS 6       // edge streams per gather block
#define ACT 240    // NS*NCH active threads

typedef short bf16x8 __attribute__((ext_vector_type(8)));
typedef unsigned short u16;
typedef u16 u16x8 __attribute__((ext_vector_type(8)));
typedef u16 u16x4 __attribute__((ext_vector_type(4)));
typedef float f32x4 __attribute__((ext_vector_type(4)));

__device__ inline unsigned short f2b(float f) {
    union { float f; unsigned int u; } x; x.f = f;
    unsigned int r = x.u + 0x7FFF + ((x.u >> 16) & 1);
    return (unsigned short)(r >> 16);
}
__device__ inline float b2f(u16 h) {
    union { float f; unsigned int u; } x; x.u = ((unsigned int)h) << 16;
    return x.f;
}

// ---------------------------------------------------------------------------
// l2 normalize rows: one wave per row; bf16 padded output only
// ---------------------------------------------------------------------------
__global__ void k_l2norm(const float* __restrict__ x, u16* __restrict__ outb, int n) {
    int wave = blockIdx.x * (blockDim.x / WAVE) + (threadIdx.x >> 6);
    int lane = threadIdx.x & 63;
    if (wave >= n) return;
    const float* row = x + (long)wave * H;
    float s = 0.f;
    for (int j = lane; j < H; j += WAVE) { float v = row[j]; s += v * v; }
    for (int o = 32; o > 0; o >>= 1) s += __shfl_xor(s, o);
    float sc = 1.0f / fmaxf(sqrtf(s), 1e-12f);
    u16* brow = outb + (long)wave * STRB;
    for (int j = lane; j < H; j += WAVE) brow[j] = f2b(row[j] * sc);
    for (int j = H + lane; j < STRB; j += WAVE) brow[j] = 0;
}

__global__ void k_zero_int(int* p, int n) {
    int i = blockIdx.x * blockDim.x + threadIdx.x;
    int stride = gridDim.x * blockDim.x;
    for (; i < n; i += stride) p[i] = 0;
}

__global__ void k_count_deg(const int* __restrict__ ei_i, int* __restrict__ deg, int E) {
    int i = blockIdx.x * blockDim.x + threadIdx.x;
    int stride = gridDim.x * blockDim.x;
    for (; i < E; i += stride) atomicAdd(&deg[ei_i[i]], 1);
}

__global__ void k_dinv(const int* __restrict__ deg, float* __restrict__ dinv, int n) {
    int i = blockIdx.x * blockDim.x + threadIdx.x;
    int stride = gridDim.x * blockDim.x;
    for (; i < n; i += stride) {
        int d = deg[i];
        dinv[i] = (d > 0) ? 1.0f / sqrtf((float)d) : 0.0f;
    }
}

__global__ void k_scan(const int* __restrict__ deg, int* __restrict__ offsets,
                       int* __restrict__ cursor, int n) {
    __shared__ int sh[1024];
    __shared__ int carry_sh;
    int tid = threadIdx.x;
    if (tid == 0) carry_sh = 0;
    __syncthreads();
    for (int base = 0; base < n; base += 1024) {
        int v = (base + tid < n) ? deg[base + tid] : 0;
        sh[tid] = v;
        __syncthreads();
        for (int off = 1; off < 1024; off <<= 1) {
            int add = (tid >= off) ? sh[tid - off] : 0;
            __syncthreads();
            sh[tid] += add;
            __syncthreads();
        }
        int total = sh[1023];
        int exc = sh[tid] - v;
        int carry = carry_sh;
        if (base + tid < n) {
            int o = carry + exc;
            offsets[base + tid] = o;
            cursor[base + tid] = o;
        }
        __syncthreads();
        if (tid == 0) carry_sh = carry + total;
        __syncthreads();
    }
    if (tid == 0) offsets[n] = carry_sh;
}

__global__ void k_fill_csr(const int* __restrict__ ei_j, const int* __restrict__ ei_i,
                           int* __restrict__ cursor, int* __restrict__ csr_src, int E) {
    int i = blockIdx.x * blockDim.x + threadIdx.x;
    int stride = gridDim.x * blockDim.x;
    for (; i < E; i += stride) {
        int dst = ei_i[i];
        int pos = atomicAdd(&cursor[dst], 1);
        csr_src[pos] = ei_j[i];
    }
}

// ---------------------------------------------------------------------------
// W fp32 [300][300] -> padded bf16 [320][320], pads zero
// ---------------------------------------------------------------------------
__global__ void k_conv_w(const float* __restrict__ W, u16* __restrict__ Wb) {
    int idx = blockIdx.x * blockDim.x + threadIdx.x;
    int stride = gridDim.x * blockDim.x;
    for (; idx < STRB * STRB; idx += stride) {
        int r = idx / STRB, c = idx - r * STRB;
        Wb[idx] = (r < H && c < H) ? f2b(W[r * H + c]) : 0;
    }
}

// ---------------------------------------------------------------------------
// MFMA NT GEMM, BM=128 x BN=64, 1-D grid bn-fast + bijective XCD swizzle.
// A input: Xb (bf16, stride STRB).
// mode A (outb != null): bf16 rows stride STRB (pads zeroed)
// mode B: highway epilogue: g = sigmoid(acc + bias[c]);
//         val = g*xnew + (1-g)*xold;  xnew from bf16 (xnewb) or fp32 (xnewf);
//         xold from bf16 (same buffer as Xb -> L2-warm);
//         optional fp32 out (ostride) + optional bf16 mirror.
// ---------------------------------------------------------------------------
#define BM 128
#define BN 64
#define BK 32
#define LDP 40
#define NXCD 8

__global__ __launch_bounds__(256) void k_gemm_fused(
        const u16* __restrict__ Xb,
        const u16* __restrict__ Wb,
        u16* __restrict__ outb,
        const float* __restrict__ hwbias,
        const u16* __restrict__ xnewb, const float* __restrict__ xnewf,
        const u16* __restrict__ xold,
        float* __restrict__ outf, long ostride,
        u16* __restrict__ mirror,
        int n_rows) {
    __shared__ __align__(16) short As[BM * LDP];
    __shared__ __align__(16) short Bs[BN * LDP];
    const int tid = threadIdx.x;

    // bijective XCD swizzle (nwg may not be divisible by 8)
    const int nwg = gridDim.x;
    const int q = nwg / NXCD, r = nwg % NXCD;
    const int xcd = blockIdx.x % NXCD, idx = blockIdx.x / NXCD;
    const int wgid = (xcd < r ? xcd * (q + 1) : r * (q + 1) + (xcd - r) * q) + idx;
    const int bm = (wgid / 5) * BM;
    const int bn = (wgid % 5) * BN;

    const int lane = tid & 63;
    const int wid = tid >> 6;
    const int wr = wid >> 1;
    const int wc = wid & 1;
    const int lrow = lane & 15;
    const int kgrp = lane >> 4;

    f32x4 acc[4][2];
    #pragma unroll
    for (int m = 0; m < 4; m++)
        #pragma unroll
        for (int n = 0; n < 2; n++) acc[m][n] = (f32x4){0.f, 0.f, 0.f, 0.f};

    for (int k0 = 0; k0 < STRB; k0 += BK) {
        // A staging: 128x32, 512 u16x8 chunks, 2/thread
        #pragma unroll
        for (int i = 0; i < 2; ++i) {
            int qq = tid + i * 256;
            int rr = qq >> 2, c = (qq & 3) << 3;
            int gr = bm + rr;
            u16x8 v = {0, 0, 0, 0, 0, 0, 0, 0};
            if (gr < n_rows) v = *(const u16x8*)&Xb[(long)gr * STRB + k0 + c];
            *(u16x8*)&As[rr * LDP + c] = v;
        }
        // W staging: 64x32 bf16, 256 chunks, 1/thread
        {
            int rr = tid >> 2, c = (tid & 3) << 3;
            u16x8 v = *(const u16x8*)&Wb[(long)(bn + rr) * STRB + k0 + c];
            *(u16x8*)&Bs[rr * LDP + c] = v;
        }
        __syncthreads();

        bf16x8 af[4], bfr[2];
        #pragma unroll
        for (int m = 0; m < 4; m++) {
            int row = wr * 64 + m * 16 + lrow;
            af[m] = *(const bf16x8*)&As[row * LDP + kgrp * 8];
        }
        #pragma unroll
        for (int n = 0; n < 2; n++) {
            int col = wc * 32 + n * 16 + lrow;
            bfr[n] = *(const bf16x8*)&Bs[col * LDP + kgrp * 8];
        }
        #pragma unroll
        for (int m = 0; m < 4; m++)
            #pragma unroll
            for (int n = 0; n < 2; n++)
                acc[m][n] = __builtin_amdgcn_mfma_f32_16x16x32_bf16(af[m], bfr[n], acc[m][n], 0, 0, 0);
        __syncthreads();
    }

    if (outb) {
        #pragma unroll
        for (int m = 0; m < 4; m++)
            #pragma unroll
            for (int n = 0; n < 2; n++) {
                int gc = bn + wc * 32 + n * 16 + lrow;
                if (gc >= STRB) continue;
                #pragma unroll
                for (int rr = 0; rr < 4; rr++) {
                    int gr = bm + wr * 64 + m * 16 + kgrp * 4 + rr;
                    if (gr < n_rows) outb[(long)gr * STRB + gc] = (gc < H) ? f2b(acc[m][n][rr]) : 0;
                }
            }
    } else {
        #pragma unroll
        for (int m = 0; m < 4; m++)
            #pragma unroll
            for (int n = 0; n < 2; n++) {
                int gc = bn + wc * 32 + n * 16 + lrow;
                if (gc >= STRB) continue;
                bool colv = (gc < H);
                float bb = colv ? hwbias[gc] : 0.f;
                #pragma unroll
                for (int rr = 0; rr < 4; rr++) {
                    int gr = bm + wr * 64 + m * 16 + kgrp * 4 + rr;
                    if (gr >= n_rows) continue;
                    if (colv) {
                        float pre = acc[m][n][rr] + bb;
                        float g = 1.0f / (1.0f + __expf(-pre));
                        float xn = xnewb ? b2f(xnewb[(long)gr * STRB + gc])
                                         : xnewf[(long)gr * H + gc];
                        float xo = b2f(xold[(long)gr * STRB + gc]);
                        float val = g * xn + (1.0f - g) * xo;
                        if (outf) outf[(long)gr * ostride + gc] = val;
                        if (mirror) mirror[(long)gr * STRB + gc] = f2b(val);
                    } else if (mirror) {
                        mirror[(long)gr * STRB + gc] = 0;
                    }
                }
            }
    }
}

// ---------------------------------------------------------------------------
// GCN gather from bf16 rows -> bf16 padded output
// ---------------------------------------------------------------------------
__global__ __launch_bounds__(256) void k_gcn_gather_b(const u16* __restrict__ xb,
                                                      const float* __restrict__ dinv,
                                                      const int* __restrict__ offs,
                                                      const int* __restrict__ csr,
                                                      u16* __restrict__ outb) {
    int i = blockIdx.x;
    int t = threadIdx.x;
    int esub = t / NCH;
    int chunk = t - esub * NCH;
    bool active = (t < ACT);
    int start = offs[i], end = offs[i + 1];
    __shared__ float wsh[256];
    __shared__ int ssh[256];
    __shared__ float redbuf[NS * STRB];
    float accv[8] = {0.f, 0.f, 0.f, 0.f, 0.f, 0.f, 0.f, 0.f};
    float di = dinv[i];
    for (int cbase = start; cbase < end; cbase += 256) {
        int p = cbase + t;
        if (p < end) {
            int src = csr[p];
            ssh[t] = src;
            wsh[t] = di * dinv[src];
        }
        __syncthreads();
        int cnt = min(256, end - cbase);
        if (active) {
            for (int q = esub; q < cnt; q += NS) {
                float w = wsh[q];
                const u16* row = xb + (long)ssh[q] * STRB;
                u16x8 v = *(const u16x8*)&row[chunk * 8];
                #pragma unroll
                for (int j = 0; j < 8; j++) accv[j] += w * b2f(v[j]);
            }
        }
        __syncthreads();
    }
    if (active) {
        #pragma unroll
        for (int j = 0; j < 8; j++) redbuf[esub * STRB + chunk * 8 + j] = accv[j];
    }
    __syncthreads();
    u16* orow = outb + (long)i * STRB;
    for (int c = t; c < STRB; c += 256) {
        float s = 0.f;
        if (c < H) {
            s = redbuf[c] + redbuf[STRB + c] + redbuf[2 * STRB + c]
              + redbuf[3 * STRB + c] + redbuf[4 * STRB + c] + redbuf[5 * STRB + c];
            s = fmaxf(s, 0.f);
        }
        orow[c] = f2b(s);
    }
}

// ---------------------------------------------------------------------------
// dual dot from bf16 mirror: one wave per row
// ---------------------------------------------------------------------------
__global__ void k_dual_dot_b(const u16* __restrict__ xb,
                             const float* __restrict__ ai, const float* __restrict__ aj,
                             float* __restrict__ s_i, float* __restrict__ s_j, int n) {
    int wave = blockIdx.x * (blockDim.x / WAVE) + (threadIdx.x >> 6);
    int lane = threadIdx.x & 63;
    if (wave >= n) return;
    const u16* row = xb + (long)wave * STRB;
    float d0 = 0.f, d1 = 0.f;
    {
        u16x4 v = *(const u16x4*)&row[lane * 4];
        float4 a4 = *(const float4*)&ai[lane * 4];
        float4 j4 = *(const float4*)&aj[lane * 4];
        float x0 = b2f(v[0]), x1 = b2f(v[1]), x2 = b2f(v[2]), x3 = b2f(v[3]);
        d0 = x0 * a4.x + x1 * a4.y + x2 * a4.z + x3 * a4.w;
        d1 = x0 * j4.x + x1 * j4.y + x2 * j4.z + x3 * j4.w;
    }
    if (lane < 11) {  // cols 256..299 (44 elems = 11 lanes x 4)
        u16x4 v = *(const u16x4*)&row[256 + lane * 4];
        float4 a4 = *(const float4*)&ai[256 + lane * 4];
        float4 j4 = *(const float4*)&aj[256 + lane * 4];
        float x0 = b2f(v[0]), x1 = b2f(v[1]), x2 = b2f(v[2]), x3 = b2f(v[3]);
        d0 += x0 * a4.x + x1 * a4.y + x2 * a4.z + x3 * a4.w;
        d1 += x0 * j4.x + x1 * j4.y + x2 * j4.z + x3 * j4.w;
    }
    for (int o = 32; o > 0; o >>= 1) { d0 += __shfl_down(d0, o); d1 += __shfl_down(d1, o); }
    if (lane == 0) { s_i[wave] = d0; s_j[wave] = d1; }
}

// ---------------------------------------------------------------------------
// GAT gather from bf16 rows, fused segment-softmax.
// Output: outb16 (bf16 padded) if non-null, else fp32 (out_stride/out_off).
// ---------------------------------------------------------------------------
__global__ __launch_bounds__(256) void k_gat_gather_b(const u16* __restrict__ xb,
                                                      const float* __restrict__ s_i_arr,
                                                      const float* __restrict__ s_j_arr,
                                                      const int* __restrict__ offs,
                                                      const int* __restrict__ csr,
                                                      u16* __restrict__ outb16,
                                                      float* __restrict__ outf, long out_stride,
                                                      int out_off) {
    int i = blockIdx.x;
    int t = threadIdx.x;
    int esub = t / NCH;
    int chunk = t - esub * NCH;
    bool active = (t < ACT);
    int start = offs[i], end = offs[i + 1];
    int deg = end - start;
    __shared__ float wsh[256];
    __shared__ int ssh[256];
    __shared__ float redm[256];
    __shared__ float reds[256];
    __shared__ float redbuf[NS * STRB];
    float accv[8] = {0.f, 0.f, 0.f, 0.f, 0.f, 0.f, 0.f, 0.f};

    if (deg > 0) {
        float si = s_i_arr[i];
        if (deg <= 64) {
            if (t < 64) {
                float sc = 0.f;
                if (t < deg) {
                    int src = csr[start + t];
                    ssh[t] = src;
                    sc = si + s_j_arr[src];
                    sc = (sc >= 0.f) ? sc : 0.01f * sc;
                }
                float mm = (t < deg) ? sc : -1e30f;
                for (int o = 32; o > 0; o >>= 1) mm = fmaxf(mm, __shfl_xor(mm, o));
                float ex = (t < deg) ? __expf(sc - mm) : 0.f;
                float ss = ex;
                for (int o = 32; o > 0; o >>= 1) ss += __shfl_xor(ss, o);
                if (t < deg) wsh[t] = ex / (ss + 1e-16f);
            }
            __syncthreads();
            if (active) {
                for (int q = esub; q < deg; q += NS) {
                    float w = wsh[q];
                    const u16* row = xb + (long)ssh[q] * STRB;
                    u16x8 v = *(const u16x8*)&row[chunk * 8];
                    #pragma unroll
                    for (int j = 0; j < 8; j++) accv[j] += w * b2f(v[j]);
                }
            }
        } else if (deg <= 256) {
            float sc = 0.f;
            float m_t = -1e30f, s_t = 0.f;
            if (t < deg) {
                int src = csr[start + t];
                sc = si + s_j_arr[src];
                sc = (sc >= 0.f) ? sc : 0.01f * sc;
                m_t = sc; s_t = 1.0f;
                ssh[t] = src;
            }
            redm[t] = m_t; reds[t] = s_t;
            __syncthreads();
            for (int o = 128; o > 0; o >>= 1) {
                if (t < o) {
                    float m1 = redm[t], m2 = redm[t + o];
                    float mm = fmaxf(m1, m2);
                    reds[t] = reds[t] * __expf(m1 - mm) + reds[t + o] * __expf(m2 - mm);
                    redm[t] = mm;
                }
                __syncthreads();
            }
            float m = redm[0];
            float inv = 1.0f / (reds[0] + 1e-16f);
            if (t < deg) wsh[t] = __expf(sc - m) * inv;
            __syncthreads();
            if (active) {
                for (int q = esub; q < deg; q += NS) {
                    float w = wsh[q];
                    const u16* row = xb + (long)ssh[q] * STRB;
                    u16x8 v = *(const u16x8*)&row[chunk * 8];
                    #pragma unroll
                    for (int j = 0; j < 8; j++) accv[j] += w * b2f(v[j]);
                }
            }
        } else {
            float m_t = -1e30f, s_t = 0.f;
            for (int p = start + t; p < end; p += 256) {
                float sc = si + s_j_arr[csr[p]];
                sc = (sc >= 0.f) ? sc : 0.01f * sc;
                if (sc > m_t) { s_t = s_t * __expf(m_t - sc) + 1.0f; m_t = sc; }
                else s_t += __expf(sc - m_t);
            }
            redm[t] = m_t; reds[t] = s_t;
            __syncthreads();
            for (int o = 128; o > 0; o >>= 1) {
                if (t < o) {
                    float m1 = redm[t], m2 = redm[t + o];
                    float mm = fmaxf(m1, m2);
                    reds[t] = reds[t] * __expf(m1 - mm) + reds[t + o] * __expf(m2 - mm);
                    redm[t] = mm;
                }
                __syncthreads();
            }
            float m = redm[0];
            float inv = 1.0f / (reds[0] + 1e-16f);
            __syncthreads();
            for (int cbase = start; cbase < end; cbase += 256) {
                int p = cbase + t;
                if (p < end) {
                    int src = csr[p];
                    float sc = si + s_j_arr[src];
                    sc = (sc >= 0.f) ? sc : 0.01f * sc;
                    ssh[t] = src;
                    wsh[t] = __expf(sc - m) * inv;
                }
                __syncthreads();
                int cnt = min(256, end - cbase);
                if (active) {
                    for (int q = esub; q < cnt; q += NS) {
                        float w = wsh[q];
                        const u16* row = xb + (long)ssh[q] * STRB;
                        u16x8 v = *(const u16x8*)&row[chunk * 8];
                        #pragma unroll
                        for (int j = 0; j < 8; j++) accv[j] += w * b2f(v[j]);
                    }
                }
                __syncthreads();
            }
        }
    }
    if (active) {
        #pragma unroll
        for (int j = 0; j < 8; j++) redbuf[esub * STRB + chunk * 8 + j] = accv[j];
    }
    __syncthreads();
    if (outb16) {
        u16* orow = outb16 + (long)i * STRB;
        for (int c = t; c < STRB; c += 256) {
            float s = 0.f;
            if (c < H) {
                s = redbuf[c] + redbuf[STRB + c] + redbuf[2 * STRB + c]
                  + redbuf[3 * STRB + c] + redbuf[4 * STRB + c] + redbuf[5 * STRB + c];
                s = fmaxf(s, 0.f);
            }
            orow[c] = f2b(s);
        }
    } else {
        for (int c = t; c < H; c += 256) {
            float s = redbuf[c] + redbuf[STRB + c] + redbuf[2 * STRB + c]
                    + redbuf[3 * STRB + c] + redbuf[4 * STRB + c] + redbuf[5 * STRB + c];
            outf[(long)i * out_stride + out_off + c] = fmaxf(s, 0.f);
        }
    }
}

// ---------------------------------------------------------------------------
// launch
// ---------------------------------------------------------------------------
extern "C" void kernel_launch(void* const* d_in, const int* in_sizes, int n_in,
                              void* d_out, int out_size, void* d_ws, size_t ws_size,
                              hipStream_t stream) {
    const float* x_e     = (const float*)d_in[0];
    const int*   ei_all  = (const int*)d_in[3];
    const float* gcn1_W  = (const float*)d_in[5];
    const float* hw1_W   = (const float*)d_in[6];
    const float* hw1_b   = (const float*)d_in[7];
    const float* gat1_ai = (const float*)d_in[8];
    const float* gat1_aj = (const float*)d_in[9];
    const float* ghw1_W  = (const float*)d_in[10];
    const float* ghw1_b  = (const float*)d_in[11];
    const float* gat2_ai = (const float*)d_in[12];
    const float* gat2_aj = (const float*)d_in[13];
    const float* ghw2_W  = (const float*)d_in[14];
    const float* ghw2_b  = (const float*)d_in[15];
    const float* gat_ai  = (const float*)d_in[16];
    const float* gat_aj  = (const float*)d_in[17];

    const int N = in_sizes[0] / H;
    const int E = in_sizes[3] / 2;
    const int* ei_j = ei_all;
    const int* ei_i = ei_all + E;

    float* out = (float*)d_out;

    // rotating bf16 buffers (N*STRB u16 = 32 MB each):
    //  W0: x0b (steps 1-5)
    //  W1: hb (3-4), g1b (7-8)
    //  W2: gcnb (4-5), x3b (8-10), xeb (11-13)
    //  W3: x2b (5-11)
    //  G2F (fp32, 60 MB) overlaps W0+W1: gat2_out (10-11); W0/W1 contents dead by then
    size_t NSB = (size_t)N * STRB;
    u16*   W0   = (u16*)d_ws;
    u16*   W1   = W0 + NSB;
    u16*   W2   = W1 + NSB;
    u16*   W3   = W2 + NSB;
    float* G2F  = (float*)d_ws;              // spans [0, 60MB) ⊂ W0+W1 (64MB)
    float* sbi  = (float*)(W3 + NSB);
    float* sbj  = sbi + N;
    float* dinv = sbj + N;
    int*   deg  = (int*)(dinv + N);
    int*   offs = deg + N;
    int*   cursor = offs + (N + 1);
    int*   csr  = cursor + N;                // E ints
    u16*   wb0  = (u16*)(csr + E);           // 4 x 320x320 bf16 weights
    u16*   wb1  = wb0 + STRB * STRB;
    u16*   wb2  = wb1 + STRB * STRB;
    u16*   wb3  = wb2 + STRB * STRB;

    dim3 blk256(256);
    int rowsPerBlock = 256 / WAVE;
    dim3 gridRows((N + rowsPerBlock - 1) / rowsPerBlock);
    dim3 gridNode(N);
    dim3 gridE(2048);
    dim3 gridW(100);
    dim3 gridGemm(((N + BM - 1) / BM) * 5);

    // 1. x0b = bf16(l2_normalize(x_e)) -> W0
    hipLaunchKernelGGL(k_l2norm, gridRows, blk256, 0, stream, x_e, W0, N);

    // 2. CSR build + weight conversion
    hipLaunchKernelGGL(k_zero_int, dim3(256), blk256, 0, stream, deg, N);
    hipLaunchKernelGGL(k_count_deg, gridE, blk256, 0, stream, ei_i, deg, E);
    hipLaunchKernelGGL(k_dinv, dim3(256), blk256, 0, stream, deg, dinv, N);
    hipLaunchKernelGGL(k_scan, dim3(1), dim3(1024), 0, stream, deg, offs, cursor, N);
    hipLaunchKernelGGL(k_fill_csr, gridE, blk256, 0, stream, ei_j, ei_i, cursor, csr, E);
    hipLaunchKernelGGL(k_conv_w, gridW, blk256, 0, stream, gcn1_W, wb0);
    hipLaunchKernelGGL(k_conv_w, gridW, blk256, 0, stream, hw1_W, wb1);
    hipLaunchKernelGGL(k_conv_w, gridW, blk256, 0, stream, ghw1_W, wb2);
    hipLaunchKernelGGL(k_conv_w, gridW, blk256, 0, stream, ghw2_W, wb3);

    // 3. hb = bf16(x0 @ gcn1_W.T) -> W1
    hipLaunchKernelGGL(k_gemm_fused, gridGemm, blk256, 0, stream,
                       W0, wb0, W1,
                       (const float*)nullptr, (const u16*)nullptr, (const float*)nullptr,
                       (const u16*)nullptr, (float*)nullptr, (long)0, (u16*)nullptr, N);

    // 4. gcnb -> W2
    hipLaunchKernelGGL(k_gcn_gather_b, gridNode, blk256, 0, stream, W1, dinv, offs, csr, W2);

    // 5. x2b = hw(x0b, gcnb) fused: pre = x0b@hw1_W.T -> mirror W3
    hipLaunchKernelGGL(k_gemm_fused, gridGemm, blk256, 0, stream,
                       W0, wb1, (u16*)nullptr,
                       hw1_b, W2, (const float*)nullptr, W0,
                       (float*)nullptr, (long)0, W3, N);

    // 6. dots for GAT1 from x2b
    hipLaunchKernelGGL(k_dual_dot_b, gridRows, blk256, 0, stream, W3, gat1_ai, gat1_aj, sbi, sbj, N);

    // 7. GAT1 gather on x2b -> g1b (W1)
    hipLaunchKernelGGL(k_gat_gather_b, gridNode, blk256, 0, stream, W3, sbi, sbj, offs, csr,
                       W1, (float*)nullptr, (long)0, 0);

    // 8. x3b = hw(x2b, g1b) fused: pre = x2b@ghw1_W.T -> mirror W2
    hipLaunchKernelGGL(k_gemm_fused, gridGemm, blk256, 0, stream,
                       W3, wb2, (u16*)nullptr,
                       ghw1_b, W1, (const float*)nullptr, W3,
                       (float*)nullptr, (long)0, W2, N);

    // 9. dots for GAT2 from x3b
    hipLaunchKernelGGL(k_dual_dot_b, gridRows, blk256, 0, stream, W2, gat2_ai, gat2_aj, sbi, sbj, N);

    // 10. GAT2 gather on x3b -> G2F (fp32, contiguous stride H)
    hipLaunchKernelGGL(k_gat_gather_b, gridNode, blk256, 0, stream, W2, sbi, sbj, offs, csr,
                       (u16*)nullptr, G2F, (long)H, 0);

    // 11. xe = hw(x2b, G2F) fused: pre = x2b@ghw2_W.T -> d_out[:,0:300] fp32 + mirror xeb (W2)
    hipLaunchKernelGGL(k_gemm_fused, gridGemm, blk256, 0, stream,
                       W3, wb3, (u16*)nullptr,
                       ghw2_b, (const u16*)nullptr, G2F, W3,
                       out, (long)(2 * H), W2, N);

    // 12. dots for final GAT from xeb
    hipLaunchKernelGGL(k_dual_dot_b, gridRows, blk256, 0, stream, W2, gat_ai, gat_aj, sbi, sbj, N);

    // 13. final GAT gather on xeb -> d_out[:,300:600]
    hipLaunchKernelGGL(k_gat_gather_b, gridNode, blk256, 0, stream, W2, sbi, sbj, offs, csr,
                       (u16*)nullptr, out, (long)(2 * H), H);
}

// Round 10
// 809.787 us; speedup vs baseline: 1.2752x; 1.0729x over previous
//
#include <hip/hip_runtime.h>
#include <hip/hip_bf16.h>
#include <math.h>

#define H 300
#define WAVE 64
#define STRB 320   // padded bf16 row stride (640 B; 40 chunks of 16 B)
#define NCP 20     // 32B chunk-pairs per row
#define NSS 12     // edge streams per gather block
#define ACT 240    // NSS*NCP active threads
#define SCB 1024

typedef short bf16x8 __attribute__((ext_vector_type(8)));
typedef unsigned short u16;
typedef u16 u16x8 __attribute__((ext_vector_type(8)));
typedef u16 u16x4 __attribute__((ext_vector_type(4)));
typedef float f32x4 __attribute__((ext_vector_type(4)));

__device__ inline unsigned short f2b(float f) {
    union { float f; unsigned int u; } x; x.f = f;
    unsigned int r = x.u + 0x7FFF + ((x.u >> 16) & 1);
    return (unsigned short)(r >> 16);
}
__device__ inline float b2f(u16 h) {
    union { float f; unsigned int u; } x; x.u = ((unsigned int)h) << 16;
    return x.f;
}

// ---------------------------------------------------------------------------
// l2 normalize rows: one wave per row; bf16 padded output only
// ---------------------------------------------------------------------------
__global__ void k_l2norm(const float* __restrict__ x, u16* __restrict__ outb, int n) {
    int wave = blockIdx.x * (blockDim.x / WAVE) + (threadIdx.x >> 6);
    int lane = threadIdx.x & 63;
    if (wave >= n) return;
    const float* row = x + (long)wave * H;
    float s = 0.f;
    for (int j = lane; j < H; j += WAVE) { float v = row[j]; s += v * v; }
    for (int o = 32; o > 0; o >>= 1) s += __shfl_xor(s, o);
    float sc = 1.0f / fmaxf(sqrtf(s), 1e-12f);
    u16* brow = outb + (long)wave * STRB;
    for (int j = lane; j < H; j += WAVE) brow[j] = f2b(row[j] * sc);
    for (int j = H + lane; j < STRB; j += WAVE) brow[j] = 0;
}

__global__ void k_zero_int(int* p, int n) {
    int i = blockIdx.x * blockDim.x + threadIdx.x;
    int stride = gridDim.x * blockDim.x;
    for (; i < n; i += stride) p[i] = 0;
}

__global__ void k_count_deg(const int* __restrict__ ei_i, int* __restrict__ deg, int E) {
    int i = blockIdx.x * blockDim.x + threadIdx.x;
    int stride = gridDim.x * blockDim.x;
    for (; i < E; i += stride) atomicAdd(&deg[ei_i[i]], 1);
}

__global__ void k_dinv(const int* __restrict__ deg, float* __restrict__ dinv, int n) {
    int i = blockIdx.x * blockDim.x + threadIdx.x;
    int stride = gridDim.x * blockDim.x;
    for (; i < n; i += stride) {
        int d = deg[i];
        dinv[i] = (d > 0) ? 1.0f / sqrtf((float)d) : 0.0f;
    }
}

// ---------------------------------------------------------------------------
// 3-kernel parallel exclusive scan of deg -> offs(+cursor), offs[n]=total
// ---------------------------------------------------------------------------
__global__ void k_scan_local(const int* __restrict__ deg, int* __restrict__ offs,
                             int* __restrict__ btot, int n) {
    __shared__ int sh[SCB];
    int base = blockIdx.x * SCB;
    int tid = threadIdx.x;
    int v = (base + tid < n) ? deg[base + tid] : 0;
    sh[tid] = v;
    __syncthreads();
    for (int off = 1; off < SCB; off <<= 1) {
        int add = (tid >= off) ? sh[tid - off] : 0;
        __syncthreads();
        sh[tid] += add;
        __syncthreads();
    }
    if (base + tid < n) offs[base + tid] = sh[tid] - v;   // exclusive, block-local
    if (tid == SCB - 1) btot[blockIdx.x] = sh[tid];
}

__global__ void k_scan_tots(const int* __restrict__ btot, int* __restrict__ bpre,
                            int nb, int* __restrict__ total_out) {
    int l = threadIdx.x;   // single wave of 64; nb <= 64
    int v = (l < nb) ? btot[l] : 0;
    int own = v;
    for (int o = 1; o < 64; o <<= 1) {
        int u = __shfl_up(v, o);
        if (l >= o) v += u;
    }
    if (l < nb) bpre[l] = v - own;          // exclusive prefix
    if (l == 63) total_out[0] = v;          // grand total
}

__global__ void k_scan_apply(int* __restrict__ offs, const int* __restrict__ bpre,
                             int* __restrict__ cursor, int n) {
    int i = blockIdx.x * blockDim.x + threadIdx.x;
    int stride = gridDim.x * blockDim.x;
    for (; i < n; i += stride) {
        int o = offs[i] + bpre[i / SCB];
        offs[i] = o;
        cursor[i] = o;
    }
}

__global__ void k_fill_csr(const int* __restrict__ ei_j, const int* __restrict__ ei_i,
                           int* __restrict__ cursor, int* __restrict__ csr_src, int E) {
    int i = blockIdx.x * blockDim.x + threadIdx.x;
    int stride = gridDim.x * blockDim.x;
    for (; i < E; i += stride) {
        int dst = ei_i[i];
        int pos = atomicAdd(&cursor[dst], 1);
        csr_src[pos] = ei_j[i];
    }
}

// ---------------------------------------------------------------------------
// W fp32 [300][300] -> padded bf16 [320][320], pads zero
// ---------------------------------------------------------------------------
__global__ void k_conv_w(const float* __restrict__ W, u16* __restrict__ Wb) {
    int idx = blockIdx.x * blockDim.x + threadIdx.x;
    int stride = gridDim.x * blockDim.x;
    for (; idx < STRB * STRB; idx += stride) {
        int r = idx / STRB, c = idx - r * STRB;
        Wb[idx] = (r < H && c < H) ? f2b(W[r * H + c]) : 0;
    }
}

// ---------------------------------------------------------------------------
// MFMA NT GEMM, BM=128 x BN=64, 1-D grid bn-fast + bijective XCD swizzle.
// ---------------------------------------------------------------------------
#define BM 128
#define BN 64
#define BK 32
#define LDP 40
#define NXCD 8

__global__ __launch_bounds__(256) void k_gemm_fused(
        const u16* __restrict__ Xb,
        const u16* __restrict__ Wb,
        u16* __restrict__ outb,
        const float* __restrict__ hwbias,
        const u16* __restrict__ xnewb, const float* __restrict__ xnewf,
        const u16* __restrict__ xold,
        float* __restrict__ outf, long ostride,
        u16* __restrict__ mirror,
        int n_rows) {
    __shared__ __align__(16) short As[BM * LDP];
    __shared__ __align__(16) short Bs[BN * LDP];
    const int tid = threadIdx.x;

    const int nwg = gridDim.x;
    const int q = nwg / NXCD, r = nwg % NXCD;
    const int xcd = blockIdx.x % NXCD, idx = blockIdx.x / NXCD;
    const int wgid = (xcd < r ? xcd * (q + 1) : r * (q + 1) + (xcd - r) * q) + idx;
    const int bm = (wgid / 5) * BM;
    const int bn = (wgid % 5) * BN;

    const int lane = tid & 63;
    const int wid = tid >> 6;
    const int wr = wid >> 1;
    const int wc = wid & 1;
    const int lrow = lane & 15;
    const int kgrp = lane >> 4;

    f32x4 acc[4][2];
    #pragma unroll
    for (int m = 0; m < 4; m++)
        #pragma unroll
        for (int n = 0; n < 2; n++) acc[m][n] = (f32x4){0.f, 0.f, 0.f, 0.f};

    for (int k0 = 0; k0 < STRB; k0 += BK) {
        #pragma unroll
        for (int i = 0; i < 2; ++i) {
            int qq = tid + i * 256;
            int rr = qq >> 2, c = (qq & 3) << 3;
            int gr = bm + rr;
            u16x8 v = {0, 0, 0, 0, 0, 0, 0, 0};
            if (gr < n_rows) v = *(const u16x8*)&Xb[(long)gr * STRB + k0 + c];
            *(u16x8*)&As[rr * LDP + c] = v;
        }
        {
            int rr = tid >> 2, c = (tid & 3) << 3;
            u16x8 v = *(const u16x8*)&Wb[(long)(bn + rr) * STRB + k0 + c];
            *(u16x8*)&Bs[rr * LDP + c] = v;
        }
        __syncthreads();

        bf16x8 af[4], bfr[2];
        #pragma unroll
        for (int m = 0; m < 4; m++) {
            int row = wr * 64 + m * 16 + lrow;
            af[m] = *(const bf16x8*)&As[row * LDP + kgrp * 8];
        }
        #pragma unroll
        for (int n = 0; n < 2; n++) {
            int col = wc * 32 + n * 16 + lrow;
            bfr[n] = *(const bf16x8*)&Bs[col * LDP + kgrp * 8];
        }
        #pragma unroll
        for (int m = 0; m < 4; m++)
            #pragma unroll
            for (int n = 0; n < 2; n++)
                acc[m][n] = __builtin_amdgcn_mfma_f32_16x16x32_bf16(af[m], bfr[n], acc[m][n], 0, 0, 0);
        __syncthreads();
    }

    if (outb) {
        #pragma unroll
        for (int m = 0; m < 4; m++)
            #pragma unroll
            for (int n = 0; n < 2; n++) {
                int gc = bn + wc * 32 + n * 16 + lrow;
                if (gc >= STRB) continue;
                #pragma unroll
                for (int rr = 0; rr < 4; rr++) {
                    int gr = bm + wr * 64 + m * 16 + kgrp * 4 + rr;
                    if (gr < n_rows) outb[(long)gr * STRB + gc] = (gc < H) ? f2b(acc[m][n][rr]) : 0;
                }
            }
    } else {
        #pragma unroll
        for (int m = 0; m < 4; m++)
            #pragma unroll
            for (int n = 0; n < 2; n++) {
                int gc = bn + wc * 32 + n * 16 + lrow;
                if (gc >= STRB) continue;
                bool colv = (gc < H);
                float bb = colv ? hwbias[gc] : 0.f;
                #pragma unroll
                for (int rr = 0; rr < 4; rr++) {
                    int gr = bm + wr * 64 + m * 16 + kgrp * 4 + rr;
                    if (gr >= n_rows) continue;
                    if (colv) {
                        float pre = acc[m][n][rr] + bb;
                        float g = 1.0f / (1.0f + __expf(-pre));
                        float xn = xnewb ? b2f(xnewb[(long)gr * STRB + gc])
                                         : xnewf[(long)gr * H + gc];
                        float xo = b2f(xold[(long)gr * STRB + gc]);
                        float val = g * xn + (1.0f - g) * xo;
                        if (outf) outf[(long)gr * ostride + gc] = val;
                        if (mirror) mirror[(long)gr * STRB + gc] = f2b(val);
                    } else if (mirror) {
                        mirror[(long)gr * STRB + gc] = 0;
                    }
                }
            }
    }
}

// ---------------------------------------------------------------------------
// GCN gather from bf16 rows -> bf16 padded output. 12 streams x 20 pairs.
// ---------------------------------------------------------------------------
__global__ __launch_bounds__(256) void k_gcn_gather_b(const u16* __restrict__ xb,
                                                      const float* __restrict__ dinv,
                                                      const int* __restrict__ offs,
                                                      const int* __restrict__ csr,
                                                      u16* __restrict__ outb) {
    int i = blockIdx.x;
    int t = threadIdx.x;
    int esub = t / NCP;
    int cp = t - esub * NCP;
    bool active = (t < ACT);
    int start = offs[i], end = offs[i + 1];
    __shared__ float wsh[256];
    __shared__ int ssh[256];
    __shared__ float redbuf[NSS * STRB];
    float accv[16];
    #pragma unroll
    for (int j = 0; j < 16; j++) accv[j] = 0.f;
    float di = dinv[i];
    for (int cbase = start; cbase < end; cbase += 256) {
        int p = cbase + t;
        if (p < end) {
            int src = csr[p];
            ssh[t] = src;
            wsh[t] = di * dinv[src];
        }
        __syncthreads();
        int cnt = min(256, end - cbase);
        if (active) {
            for (int q = esub; q < cnt; q += NSS) {
                float w = wsh[q];
                const u16* row = xb + (long)ssh[q] * STRB + cp * 16;
                u16x8 v0 = *(const u16x8*)row;
                u16x8 v1 = *(const u16x8*)(row + 8);
                #pragma unroll
                for (int j = 0; j < 8; j++) accv[j] += w * b2f(v0[j]);
                #pragma unroll
                for (int j = 0; j < 8; j++) accv[8 + j] += w * b2f(v1[j]);
            }
        }
        __syncthreads();
    }
    if (active) {
        #pragma unroll
        for (int j = 0; j < 16; j++) redbuf[esub * STRB + cp * 16 + j] = accv[j];
    }
    __syncthreads();
    u16* orow = outb + (long)i * STRB;
    for (int c = t; c < STRB; c += 256) {
        float s = 0.f;
        if (c < H) {
            #pragma unroll
            for (int k = 0; k < NSS; k++) s += redbuf[k * STRB + c];
            s = fmaxf(s, 0.f);
        }
        orow[c] = f2b(s);
    }
}

// ---------------------------------------------------------------------------
// dual dot from bf16 mirror: one wave per row
// ---------------------------------------------------------------------------
__global__ void k_dual_dot_b(const u16* __restrict__ xb,
                             const float* __restrict__ ai, const float* __restrict__ aj,
                             float* __restrict__ s_i, float* __restrict__ s_j, int n) {
    int wave = blockIdx.x * (blockDim.x / WAVE) + (threadIdx.x >> 6);
    int lane = threadIdx.x & 63;
    if (wave >= n) return;
    const u16* row = xb + (long)wave * STRB;
    float d0 = 0.f, d1 = 0.f;
    {
        u16x4 v = *(const u16x4*)&row[lane * 4];
        float4 a4 = *(const float4*)&ai[lane * 4];
        float4 j4 = *(const float4*)&aj[lane * 4];
        float x0 = b2f(v[0]), x1 = b2f(v[1]), x2 = b2f(v[2]), x3 = b2f(v[3]);
        d0 = x0 * a4.x + x1 * a4.y + x2 * a4.z + x3 * a4.w;
        d1 = x0 * j4.x + x1 * j4.y + x2 * j4.z + x3 * j4.w;
    }
    if (lane < 11) {
        u16x4 v = *(const u16x4*)&row[256 + lane * 4];
        float4 a4 = *(const float4*)&ai[256 + lane * 4];
        float4 j4 = *(const float4*)&aj[256 + lane * 4];
        float x0 = b2f(v[0]), x1 = b2f(v[1]), x2 = b2f(v[2]), x3 = b2f(v[3]);
        d0 += x0 * a4.x + x1 * a4.y + x2 * a4.z + x3 * a4.w;
        d1 += x0 * j4.x + x1 * j4.y + x2 * j4.z + x3 * j4.w;
    }
    for (int o = 32; o > 0; o >>= 1) { d0 += __shfl_down(d0, o); d1 += __shfl_down(d1, o); }
    if (lane == 0) { s_i[wave] = d0; s_j[wave] = d1; }
}

// ---------------------------------------------------------------------------
// GAT gather, fused segment-softmax, 12 streams x 20 pairs.
// Output: outb16 (bf16 padded) if non-null, else fp32 (out_stride/out_off).
// ---------------------------------------------------------------------------
__global__ __launch_bounds__(256) void k_gat_gather_b(const u16* __restrict__ xb,
                                                      const float* __restrict__ s_i_arr,
                                                      const float* __restrict__ s_j_arr,
                                                      const int* __restrict__ offs,
                                                      const int* __restrict__ csr,
                                                      u16* __restrict__ outb16,
                                                      float* __restrict__ outf, long out_stride,
                                                      int out_off) {
    int i = blockIdx.x;
    int t = threadIdx.x;
    int esub = t / NCP;
    int cp = t - esub * NCP;
    bool active = (t < ACT);
    int start = offs[i], end = offs[i + 1];
    int deg = end - start;
    __shared__ float wsh[256];
    __shared__ int ssh[256];
    __shared__ float redm[256];
    __shared__ float reds[256];
    __shared__ float redbuf[NSS * STRB];
    float accv[16];
    #pragma unroll
    for (int j = 0; j < 16; j++) accv[j] = 0.f;

    if (deg > 0) {
        float si = s_i_arr[i];
        if (deg <= 64) {
            if (t < 64) {
                float sc = 0.f;
                if (t < deg) {
                    int src = csr[start + t];
                    ssh[t] = src;
                    sc = si + s_j_arr[src];
                    sc = (sc >= 0.f) ? sc : 0.01f * sc;
                }
                float mm = (t < deg) ? sc : -1e30f;
                for (int o = 32; o > 0; o >>= 1) mm = fmaxf(mm, __shfl_xor(mm, o));
                float ex = (t < deg) ? __expf(sc - mm) : 0.f;
                float ss = ex;
                for (int o = 32; o > 0; o >>= 1) ss += __shfl_xor(ss, o);
                if (t < deg) wsh[t] = ex / (ss + 1e-16f);
            }
            __syncthreads();
            if (active) {
                for (int q = esub; q < deg; q += NSS) {
                    float w = wsh[q];
                    const u16* row = xb + (long)ssh[q] * STRB + cp * 16;
                    u16x8 v0 = *(const u16x8*)row;
                    u16x8 v1 = *(const u16x8*)(row + 8);
                    #pragma unroll
                    for (int j = 0; j < 8; j++) accv[j] += w * b2f(v0[j]);
                    #pragma unroll
                    for (int j = 0; j < 8; j++) accv[8 + j] += w * b2f(v1[j]);
                }
            }
        } else if (deg <= 256) {
            float sc = 0.f;
            float m_t = -1e30f, s_t = 0.f;
            if (t < deg) {
                int src = csr[start + t];
                sc = si + s_j_arr[src];
                sc = (sc >= 0.f) ? sc : 0.01f * sc;
                m_t = sc; s_t = 1.0f;
                ssh[t] = src;
            }
            redm[t] = m_t; reds[t] = s_t;
            __syncthreads();
            for (int o = 128; o > 0; o >>= 1) {
                if (t < o) {
                    float m1 = redm[t], m2 = redm[t + o];
                    float mm = fmaxf(m1, m2);
                    reds[t] = reds[t] * __expf(m1 - mm) + reds[t + o] * __expf(m2 - mm);
                    redm[t] = mm;
                }
                __syncthreads();
            }
            float m = redm[0];
            float inv = 1.0f / (reds[0] + 1e-16f);
            if (t < deg) wsh[t] = __expf(sc - m) * inv;
            __syncthreads();
            if (active) {
                for (int q = esub; q < deg; q += NSS) {
                    float w = wsh[q];
                    const u16* row = xb + (long)ssh[q] * STRB + cp * 16;
                    u16x8 v0 = *(const u16x8*)row;
                    u16x8 v1 = *(const u16x8*)(row + 8);
                    #pragma unroll
                    for (int j = 0; j < 8; j++) accv[j] += w * b2f(v0[j]);
                    #pragma unroll
                    for (int j = 0; j < 8; j++) accv[8 + j] += w * b2f(v1[j]);
                }
            }
        } else {
            float m_t = -1e30f, s_t = 0.f;
            for (int p = start + t; p < end; p += 256) {
                float sc = si + s_j_arr[csr[p]];
                sc = (sc >= 0.f) ? sc : 0.01f * sc;
                if (sc > m_t) { s_t = s_t * __expf(m_t - sc) + 1.0f; m_t = sc; }
                else s_t += __expf(sc - m_t);
            }
            redm[t] = m_t; reds[t] = s_t;
            __syncthreads();
            for (int o = 128; o > 0; o >>= 1) {
                if (t < o) {
                    float m1 = redm[t], m2 = redm[t + o];
                    float mm = fmaxf(m1, m2);
                    reds[t] = reds[t] * __expf(m1 - mm) + reds[t + o] * __expf(m2 - mm);
                    redm[t] = mm;
                }
                __syncthreads();
            }
            float m = redm[0];
            float inv = 1.0f / (reds[0] + 1e-16f);
            __syncthreads();
            for (int cbase = start; cbase < end; cbase += 256) {
                int p = cbase + t;
                if (p < end) {
                    int src = csr[p];
                    float sc = si + s_j_arr[src];
                    sc = (sc >= 0.f) ? sc : 0.01f * sc;
                    ssh[t] = src;
                    wsh[t] = __expf(sc - m) * inv;
                }
                __syncthreads();
                int cnt = min(256, end - cbase);
                if (active) {
                    for (int q = esub; q < cnt; q += NSS) {
                        float w = wsh[q];
                        const u16* row = xb + (long)ssh[q] * STRB + cp * 16;
                        u16x8 v0 = *(const u16x8*)row;
                        u16x8 v1 = *(const u16x8*)(row + 8);
                        #pragma unroll
                        for (int j = 0; j < 8; j++) accv[j] += w * b2f(v0[j]);
                        #pragma unroll
                        for (int j = 0; j < 8; j++) accv[8 + j] += w * b2f(v1[j]);
                    }
                }
                __syncthreads();
            }
        }
    }
    if (active) {
        #pragma unroll
        for (int j = 0; j < 16; j++) redbuf[esub * STRB + cp * 16 + j] = accv[j];
    }
    __syncthreads();
    if (outb16) {
        u16* orow = outb16 + (long)i * STRB;
        for (int c = t; c < STRB; c += 256) {
            float s = 0.f;
            if (c < H) {
                #pragma unroll
                for (int k = 0; k < NSS; k++) s += redbuf[k * STRB + c];
                s = fmaxf(s, 0.f);
            }
            orow[c] = f2b(s);
        }
    } else {
        for (int c = t; c < H; c += 256) {
            float s = 0.f;
            #pragma unroll
            for (int k = 0; k < NSS; k++) s += redbuf[k * STRB + c];
            outf[(long)i * out_stride + out_off + c] = fmaxf(s, 0.f);
        }
    }
}

// ---------------------------------------------------------------------------
// launch
// ---------------------------------------------------------------------------
extern "C" void kernel_launch(void* const* d_in, const int* in_sizes, int n_in,
                              void* d_out, int out_size, void* d_ws, size_t ws_size,
                              hipStream_t stream) {
    const float* x_e     = (const float*)d_in[0];
    const int*   ei_all  = (const int*)d_in[3];
    const float* gcn1_W  = (const float*)d_in[5];
    const float* hw1_W   = (const float*)d_in[6];
    const float* hw1_b   = (const float*)d_in[7];
    const float* gat1_ai = (const float*)d_in[8];
    const float* gat1_aj = (const float*)d_in[9];
    const float* ghw1_W  = (const float*)d_in[10];
    const float* ghw1_b  = (const float*)d_in[11];
    const float* gat2_ai = (const float*)d_in[12];
    const float* gat2_aj = (const float*)d_in[13];
    const float* ghw2_W  = (const float*)d_in[14];
    const float* ghw2_b  = (const float*)d_in[15];
    const float* gat_ai  = (const float*)d_in[16];
    const float* gat_aj  = (const float*)d_in[17];

    const int N = in_sizes[0] / H;
    const int E = in_sizes[3] / 2;
    const int* ei_j = ei_all;
    const int* ei_i = ei_all + E;

    float* out = (float*)d_out;

    size_t NSB = (size_t)N * STRB;
    u16*   W0   = (u16*)d_ws;
    u16*   W1   = W0 + NSB;
    u16*   W2   = W1 + NSB;
    u16*   W3   = W2 + NSB;
    float* G2F  = (float*)d_ws;              // spans [0, 60MB) ⊂ W0+W1 (64MB)
    float* sbi  = (float*)(W3 + NSB);
    float* sbj  = sbi + N;
    float* dinv = sbj + N;
    int*   deg  = (int*)(dinv + N);
    int*   offs = deg + N;                   // N+1
    int*   cursor = offs + (N + 1);
    int*   csr  = cursor + N;                // E ints
    int*   btot = csr + E;                   // 64
    int*   bpre = btot + 64;                 // 64
    u16*   wb0  = (u16*)(bpre + 64);         // 4 x 320x320 bf16 weights
    u16*   wb1  = wb0 + STRB * STRB;
    u16*   wb2  = wb1 + STRB * STRB;
    u16*   wb3  = wb2 + STRB * STRB;

    dim3 blk256(256);
    int rowsPerBlock = 256 / WAVE;
    dim3 gridRows((N + rowsPerBlock - 1) / rowsPerBlock);
    dim3 gridNode(N);
    dim3 gridE(2048);
    dim3 gridW(100);
    dim3 gridGemm(((N + BM - 1) / BM) * 5);
    int nScanB = (N + SCB - 1) / SCB;

    // 1. x0b = bf16(l2_normalize(x_e)) -> W0
    hipLaunchKernelGGL(k_l2norm, gridRows, blk256, 0, stream, x_e, W0, N);

    // 2. CSR build + weight conversion
    hipLaunchKernelGGL(k_zero_int, dim3(256), blk256, 0, stream, deg, N);
    hipLaunchKernelGGL(k_count_deg, gridE, blk256, 0, stream, ei_i, deg, E);
    hipLaunchKernelGGL(k_dinv, dim3(256), blk256, 0, stream, deg, dinv, N);
    hipLaunchKernelGGL(k_scan_local, dim3(nScanB), dim3(SCB), 0, stream, deg, offs, btot, N);
    hipLaunchKernelGGL(k_scan_tots, dim3(1), dim3(64), 0, stream, btot, bpre, nScanB, offs + N);
    hipLaunchKernelGGL(k_scan_apply, dim3(256), blk256, 0, stream, offs, bpre, cursor, N);
    hipLaunchKernelGGL(k_fill_csr, gridE, blk256, 0, stream, ei_j, ei_i, cursor, csr, E);
    hipLaunchKernelGGL(k_conv_w, gridW, blk256, 0, stream, gcn1_W, wb0);
    hipLaunchKernelGGL(k_conv_w, gridW, blk256, 0, stream, hw1_W, wb1);
    hipLaunchKernelGGL(k_conv_w, gridW, blk256, 0, stream, ghw1_W, wb2);
    hipLaunchKernelGGL(k_conv_w, gridW, blk256, 0, stream, ghw2_W, wb3);

    // 3. hb = bf16(x0 @ gcn1_W.T) -> W1
    hipLaunchKernelGGL(k_gemm_fused, gridGemm, blk256, 0, stream,
                       W0, wb0, W1,
                       (const float*)nullptr, (const u16*)nullptr, (const float*)nullptr,
                       (const u16*)nullptr, (float*)nullptr, (long)0, (u16*)nullptr, N);

    // 4. gcnb -> W2
    hipLaunchKernelGGL(k_gcn_gather_b, gridNode, blk256, 0, stream, W1, dinv, offs, csr, W2);

    // 5. x2b = hw(x0b, gcnb) fused: pre = x0b@hw1_W.T -> mirror W3
    hipLaunchKernelGGL(k_gemm_fused, gridGemm, blk256, 0, stream,
                       W0, wb1, (u16*)nullptr,
                       hw1_b, W2, (const float*)nullptr, W0,
                       (float*)nullptr, (long)0, W3, N);

    // 6. dots for GAT1 from x2b
    hipLaunchKernelGGL(k_dual_dot_b, gridRows, blk256, 0, stream, W3, gat1_ai, gat1_aj, sbi, sbj, N);

    // 7. GAT1 gather on x2b -> g1b (W1)
    hipLaunchKernelGGL(k_gat_gather_b, gridNode, blk256, 0, stream, W3, sbi, sbj, offs, csr,
                       W1, (float*)nullptr, (long)0, 0);

    // 8. x3b = hw(x2b, g1b) fused: pre = x2b@ghw1_W.T -> mirror W2
    hipLaunchKernelGGL(k_gemm_fused, gridGemm, blk256, 0, stream,
                       W3, wb2, (u16*)nullptr,
                       ghw1_b, W1, (const float*)nullptr, W3,
                       (float*)nullptr, (long)0, W2, N);

    // 9. dots for GAT2 from x3b
    hipLaunchKernelGGL(k_dual_dot_b, gridRows, blk256, 0, stream, W2, gat2_ai, gat2_aj, sbi, sbj, N);

    // 10. GAT2 gather on x3b -> G2F (fp32, contiguous stride H)
    hipLaunchKernelGGL(k_gat_gather_b, gridNode, blk256, 0, stream, W2, sbi, sbj, offs, csr,
                       (u16*)nullptr, G2F, (long)H, 0);

    // 11. xe = hw(x2b, G2F) fused: pre = x2b@ghw2_W.T -> d_out[:,0:300] fp32 + mirror xeb (W2)
    hipLaunchKernelGGL(k_gemm_fused, gridGemm, blk256, 0, stream,
                       W3, wb3, (u16*)nullptr,
                       ghw2_b, (const u16*)nullptr, G2F, W3,
                       out, (long)(2 * H), W2, N);

    // 12. dots for final GAT from xeb
    hipLaunchKernelGGL(k_dual_dot_b, gridRows, blk256, 0, stream, W2, gat_ai, gat_aj, sbi, sbj, N);

    // 13. final GAT gather on xeb -> d_out[:,300:600]
    hipLaunchKernelGGL(k_gat_gather_b, gridNode, blk256, 0, stream, W2, sbi, sbj, offs, csr,
                       (u16*)nullptr, out, (long)(2 * H), H);
}

// Round 11
// 743.625 us; speedup vs baseline: 1.3886x; 1.0890x over previous
//
#include <hip/hip_runtime.h>
#include <hip/hip_bf16.h>
#include <math.h>

#define H 300
#define WAVE 64
#define STRB 320   // padded bf16 row stride (640 B; 40 chunks of 16 B)
#define SCB 1024

typedef short bf16x8 __attribute__((ext_vector_type(8)));
typedef unsigned short u16;
typedef u16 u16x8 __attribute__((ext_vector_type(8)));
typedef u16 u16x4 __attribute__((ext_vector_type(4)));
typedef float f32x4 __attribute__((ext_vector_type(4)));

__device__ inline unsigned short f2b(float f) {
    union { float f; unsigned int u; } x; x.f = f;
    unsigned int r = x.u + 0x7FFF + ((x.u >> 16) & 1);
    return (unsigned short)(r >> 16);
}
__device__ inline float b2f(u16 h) {
    union { float f; unsigned int u; } x; x.u = ((unsigned int)h) << 16;
    return x.f;
}

// ---------------------------------------------------------------------------
// l2 normalize rows: one wave per row; bf16 padded output only
// ---------------------------------------------------------------------------
__global__ void k_l2norm(const float* __restrict__ x, u16* __restrict__ outb, int n) {
    int wave = blockIdx.x * (blockDim.x / WAVE) + (threadIdx.x >> 6);
    int lane = threadIdx.x & 63;
    if (wave >= n) return;
    const float* row = x + (long)wave * H;
    float s = 0.f;
    for (int j = lane; j < H; j += WAVE) { float v = row[j]; s += v * v; }
    for (int o = 32; o > 0; o >>= 1) s += __shfl_xor(s, o);
    float sc = 1.0f / fmaxf(sqrtf(s), 1e-12f);
    u16* brow = outb + (long)wave * STRB;
    for (int j = lane; j < H; j += WAVE) brow[j] = f2b(row[j] * sc);
    for (int j = H + lane; j < STRB; j += WAVE) brow[j] = 0;
}

__global__ void k_zero_int(int* p, int n) {
    int i = blockIdx.x * blockDim.x + threadIdx.x;
    int stride = gridDim.x * blockDim.x;
    for (; i < n; i += stride) p[i] = 0;
}

__global__ void k_count_deg(const int* __restrict__ ei_i, int* __restrict__ deg, int E) {
    int i = blockIdx.x * blockDim.x + threadIdx.x;
    int stride = gridDim.x * blockDim.x;
    for (; i < E; i += stride) atomicAdd(&deg[ei_i[i]], 1);
}

__global__ void k_dinv(const int* __restrict__ deg, float* __restrict__ dinv, int n) {
    int i = blockIdx.x * blockDim.x + threadIdx.x;
    int stride = gridDim.x * blockDim.x;
    for (; i < n; i += stride) {
        int d = deg[i];
        dinv[i] = (d > 0) ? 1.0f / sqrtf((float)d) : 0.0f;
    }
}

// ---------------------------------------------------------------------------
// 3-kernel parallel exclusive scan of deg -> offs(+cursor), offs[n]=total
// ---------------------------------------------------------------------------
__global__ void k_scan_local(const int* __restrict__ deg, int* __restrict__ offs,
                             int* __restrict__ btot, int n) {
    __shared__ int sh[SCB];
    int base = blockIdx.x * SCB;
    int tid = threadIdx.x;
    int v = (base + tid < n) ? deg[base + tid] : 0;
    sh[tid] = v;
    __syncthreads();
    for (int off = 1; off < SCB; off <<= 1) {
        int add = (tid >= off) ? sh[tid - off] : 0;
        __syncthreads();
        sh[tid] += add;
        __syncthreads();
    }
    if (base + tid < n) offs[base + tid] = sh[tid] - v;
    if (tid == SCB - 1) btot[blockIdx.x] = sh[tid];
}

__global__ void k_scan_tots(const int* __restrict__ btot, int* __restrict__ bpre,
                            int nb, int* __restrict__ total_out) {
    int l = threadIdx.x;   // single wave of 64; nb <= 64
    int v = (l < nb) ? btot[l] : 0;
    int own = v;
    for (int o = 1; o < 64; o <<= 1) {
        int u = __shfl_up(v, o);
        if (l >= o) v += u;
    }
    if (l < nb) bpre[l] = v - own;
    if (l == 63) total_out[0] = v;
}

__global__ void k_scan_apply(int* __restrict__ offs, const int* __restrict__ bpre,
                             int* __restrict__ cursor, int n) {
    int i = blockIdx.x * blockDim.x + threadIdx.x;
    int stride = gridDim.x * blockDim.x;
    for (; i < n; i += stride) {
        int o = offs[i] + bpre[i / SCB];
        offs[i] = o;
        cursor[i] = o;
    }
}

__global__ void k_fill_csr(const int* __restrict__ ei_j, const int* __restrict__ ei_i,
                           int* __restrict__ cursor, int* __restrict__ csr_src, int E) {
    int i = blockIdx.x * blockDim.x + threadIdx.x;
    int stride = gridDim.x * blockDim.x;
    for (; i < E; i += stride) {
        int dst = ei_i[i];
        int pos = atomicAdd(&cursor[dst], 1);
        csr_src[pos] = ei_j[i];
    }
}

// ---------------------------------------------------------------------------
// 4x W fp32 [300][300] -> padded bf16 [320][320], pads zero. One launch.
// ---------------------------------------------------------------------------
__global__ void k_conv_w4(const float* __restrict__ W0f, const float* __restrict__ W1f,
                          const float* __restrict__ W2f, const float* __restrict__ W3f,
                          u16* __restrict__ Wb0, u16* __restrict__ Wb1,
                          u16* __restrict__ Wb2, u16* __restrict__ Wb3) {
    int which = blockIdx.x & 3;
    const float* W = (which == 0) ? W0f : (which == 1) ? W1f : (which == 2) ? W2f : W3f;
    u16* Wb = (which == 0) ? Wb0 : (which == 1) ? Wb1 : (which == 2) ? Wb2 : Wb3;
    int idx = (blockIdx.x >> 2) * blockDim.x + threadIdx.x;
    int stride = (gridDim.x >> 2) * blockDim.x;
    for (; idx < STRB * STRB; idx += stride) {
        int r = idx / STRB, c = idx - r * STRB;
        Wb[idx] = (r < H && c < H) ? f2b(W[r * H + c]) : 0;
    }
}

// ---------------------------------------------------------------------------
// MFMA NT GEMM, BM=128 x BN=64, 1-D grid bn-fast + bijective XCD swizzle.
// ---------------------------------------------------------------------------
#define BM 128
#define BN 64
#define BK 32
#define LDP 40
#define NXCD 8

__global__ __launch_bounds__(256) void k_gemm_fused(
        const u16* __restrict__ Xb,
        const u16* __restrict__ Wb,
        u16* __restrict__ outb,
        const float* __restrict__ hwbias,
        const u16* __restrict__ xnewb, const float* __restrict__ xnewf,
        const u16* __restrict__ xold,
        float* __restrict__ outf, long ostride,
        u16* __restrict__ mirror,
        int n_rows) {
    __shared__ __align__(16) short As[BM * LDP];
    __shared__ __align__(16) short Bs[BN * LDP];
    const int tid = threadIdx.x;

    const int nwg = gridDim.x;
    const int q = nwg / NXCD, r = nwg % NXCD;
    const int xcd = blockIdx.x % NXCD, idx = blockIdx.x / NXCD;
    const int wgid = (xcd < r ? xcd * (q + 1) : r * (q + 1) + (xcd - r) * q) + idx;
    const int bm = (wgid / 5) * BM;
    const int bn = (wgid % 5) * BN;

    const int lane = tid & 63;
    const int wid = tid >> 6;
    const int wr = wid >> 1;
    const int wc = wid & 1;
    const int lrow = lane & 15;
    const int kgrp = lane >> 4;

    f32x4 acc[4][2];
    #pragma unroll
    for (int m = 0; m < 4; m++)
        #pragma unroll
        for (int n = 0; n < 2; n++) acc[m][n] = (f32x4){0.f, 0.f, 0.f, 0.f};

    for (int k0 = 0; k0 < STRB; k0 += BK) {
        #pragma unroll
        for (int i = 0; i < 2; ++i) {
            int qq = tid + i * 256;
            int rr = qq >> 2, c = (qq & 3) << 3;
            int gr = bm + rr;
            u16x8 v = {0, 0, 0, 0, 0, 0, 0, 0};
            if (gr < n_rows) v = *(const u16x8*)&Xb[(long)gr * STRB + k0 + c];
            *(u16x8*)&As[rr * LDP + c] = v;
        }
        {
            int rr = tid >> 2, c = (tid & 3) << 3;
            u16x8 v = *(const u16x8*)&Wb[(long)(bn + rr) * STRB + k0 + c];
            *(u16x8*)&Bs[rr * LDP + c] = v;
        }
        __syncthreads();

        bf16x8 af[4], bfr[2];
        #pragma unroll
        for (int m = 0; m < 4; m++) {
            int row = wr * 64 + m * 16 + lrow;
            af[m] = *(const bf16x8*)&As[row * LDP + kgrp * 8];
        }
        #pragma unroll
        for (int n = 0; n < 2; n++) {
            int col = wc * 32 + n * 16 + lrow;
            bfr[n] = *(const bf16x8*)&Bs[col * LDP + kgrp * 8];
        }
        #pragma unroll
        for (int m = 0; m < 4; m++)
            #pragma unroll
            for (int n = 0; n < 2; n++)
                acc[m][n] = __builtin_amdgcn_mfma_f32_16x16x32_bf16(af[m], bfr[n], acc[m][n], 0, 0, 0);
        __syncthreads();
    }

    if (outb) {
        #pragma unroll
        for (int m = 0; m < 4; m++)
            #pragma unroll
            for (int n = 0; n < 2; n++) {
                int gc = bn + wc * 32 + n * 16 + lrow;
                if (gc >= STRB) continue;
                #pragma unroll
                for (int rr = 0; rr < 4; rr++) {
                    int gr = bm + wr * 64 + m * 16 + kgrp * 4 + rr;
                    if (gr < n_rows) outb[(long)gr * STRB + gc] = (gc < H) ? f2b(acc[m][n][rr]) : 0;
                }
            }
    } else {
        #pragma unroll
        for (int m = 0; m < 4; m++)
            #pragma unroll
            for (int n = 0; n < 2; n++) {
                int gc = bn + wc * 32 + n * 16 + lrow;
                if (gc >= STRB) continue;
                bool colv = (gc < H);
                float bb = colv ? hwbias[gc] : 0.f;
                #pragma unroll
                for (int rr = 0; rr < 4; rr++) {
                    int gr = bm + wr * 64 + m * 16 + kgrp * 4 + rr;
                    if (gr >= n_rows) continue;
                    if (colv) {
                        float pre = acc[m][n][rr] + bb;
                        float g = 1.0f / (1.0f + __expf(-pre));
                        float xn = xnewb ? b2f(xnewb[(long)gr * STRB + gc])
                                         : xnewf[(long)gr * H + gc];
                        float xo = b2f(xold[(long)gr * STRB + gc]);
                        float val = g * xn + (1.0f - g) * xo;
                        if (outf) outf[(long)gr * ostride + gc] = val;
                        if (mirror) mirror[(long)gr * STRB + gc] = f2b(val);
                    } else if (mirror) {
                        mirror[(long)gr * STRB + gc] = 0;
                    }
                }
            }
    }
}

// ---------------------------------------------------------------------------
// GCN gather, wave-per-node: lane<40 owns one u16x8 chunk across all edges.
// No LDS, no barriers; weights/srcs broadcast via __shfl (uniform q).
// ---------------------------------------------------------------------------
__global__ __launch_bounds__(256) void k_gcn_gather_w(const u16* __restrict__ xb,
                                                      const float* __restrict__ dinv,
                                                      const int* __restrict__ offs,
                                                      const int* __restrict__ csr,
                                                      u16* __restrict__ outb, int n) {
    int node = blockIdx.x * 4 + (threadIdx.x >> 6);
    int lane = threadIdx.x & 63;
    if (node >= n) return;
    int start = offs[node], end = offs[node + 1];
    float acc[8];
    #pragma unroll
    for (int j = 0; j < 8; j++) acc[j] = 0.f;
    float di = dinv[node];
    for (int tb = start; tb < end; tb += 64) {
        int p = tb + lane;
        int src = 0; float w = 0.f;
        if (p < end) {
            src = csr[p];
            w = di * dinv[src];
        }
        int cnt = min(64, end - tb);
        for (int qq = 0; qq < cnt; qq++) {
            float wq = __shfl(w, qq);
            int sq = __shfl(src, qq);
            if (lane < 40) {
                u16x8 v = *(const u16x8*)&xb[(long)sq * STRB + lane * 8];
                #pragma unroll
                for (int j = 0; j < 8; j++) acc[j] += wq * b2f(v[j]);
            }
        }
    }
    if (lane < 40) {
        u16x8 o;
        #pragma unroll
        for (int j = 0; j < 8; j++) o[j] = f2b(fmaxf(acc[j], 0.f));
        *(u16x8*)&outb[(long)node * STRB + lane * 8] = o;
    }
}

// ---------------------------------------------------------------------------
// dual dot from bf16 mirror: one wave per row
// ---------------------------------------------------------------------------
__global__ void k_dual_dot_b(const u16* __restrict__ xb,
                             const float* __restrict__ ai, const float* __restrict__ aj,
                             float* __restrict__ s_i, float* __restrict__ s_j, int n) {
    int wave = blockIdx.x * (blockDim.x / WAVE) + (threadIdx.x >> 6);
    int lane = threadIdx.x & 63;
    if (wave >= n) return;
    const u16* row = xb + (long)wave * STRB;
    float d0 = 0.f, d1 = 0.f;
    {
        u16x4 v = *(const u16x4*)&row[lane * 4];
        float4 a4 = *(const float4*)&ai[lane * 4];
        float4 j4 = *(const float4*)&aj[lane * 4];
        float x0 = b2f(v[0]), x1 = b2f(v[1]), x2 = b2f(v[2]), x3 = b2f(v[3]);
        d0 = x0 * a4.x + x1 * a4.y + x2 * a4.z + x3 * a4.w;
        d1 = x0 * j4.x + x1 * j4.y + x2 * j4.z + x3 * j4.w;
    }
    if (lane < 11) {
        u16x4 v = *(const u16x4*)&row[256 + lane * 4];
        float4 a4 = *(const float4*)&ai[256 + lane * 4];
        float4 j4 = *(const float4*)&aj[256 + lane * 4];
        float x0 = b2f(v[0]), x1 = b2f(v[1]), x2 = b2f(v[2]), x3 = b2f(v[3]);
        d0 += x0 * a4.x + x1 * a4.y + x2 * a4.z + x3 * a4.w;
        d1 += x0 * j4.x + x1 * j4.y + x2 * j4.z + x3 * j4.w;
    }
    for (int o = 32; o > 0; o >>= 1) { d0 += __shfl_down(d0, o); d1 += __shfl_down(d1, o); }
    if (lane == 0) { s_i[wave] = d0; s_j[wave] = d1; }
}

// ---------------------------------------------------------------------------
// GAT gather, wave-per-node, fused softmax (two-pass, tiles of 64).
// Output: outb16 (bf16 padded) if non-null, else fp32 (out_stride/out_off).
// ---------------------------------------------------------------------------
__global__ __launch_bounds__(256) void k_gat_gather_w(const u16* __restrict__ xb,
                                                      const float* __restrict__ s_i_arr,
                                                      const float* __restrict__ s_j_arr,
                                                      const int* __restrict__ offs,
                                                      const int* __restrict__ csr,
                                                      u16* __restrict__ outb16,
                                                      float* __restrict__ outf, long out_stride,
                                                      int out_off, int n) {
    int node = blockIdx.x * 4 + (threadIdx.x >> 6);
    int lane = threadIdx.x & 63;
    if (node >= n) return;
    int start = offs[node], end = offs[node + 1];
    int deg = end - start;
    float acc[8];
    #pragma unroll
    for (int j = 0; j < 8; j++) acc[j] = 0.f;

    if (deg > 0) {
        float si = s_i_arr[node];
        // pass 1: per-lane online (m,s), then wave combine
        float m_t = -1e30f, s_t = 0.f;
        for (int p = start + lane; p < end; p += 64) {
            float sc = si + s_j_arr[csr[p]];
            sc = (sc >= 0.f) ? sc : 0.01f * sc;
            if (sc > m_t) { s_t = s_t * __expf(m_t - sc) + 1.0f; m_t = sc; }
            else s_t += __expf(sc - m_t);
        }
        for (int o = 32; o > 0; o >>= 1) {
            float m2 = __shfl_xor(m_t, o), s2 = __shfl_xor(s_t, o);
            float mm = fmaxf(m_t, m2);
            s_t = s_t * __expf(m_t - mm) + s2 * __expf(m2 - mm);
            m_t = mm;
        }
        float m = m_t;
        float inv = 1.0f / (s_t + 1e-16f);
        // pass 2: tiles of 64 edges
        for (int tb = start; tb < end; tb += 64) {
            int p = tb + lane;
            int src = 0; float w = 0.f;
            if (p < end) {
                src = csr[p];
                float sc = si + s_j_arr[src];
                sc = (sc >= 0.f) ? sc : 0.01f * sc;
                w = __expf(sc - m) * inv;
            }
            int cnt = min(64, end - tb);
            for (int qq = 0; qq < cnt; qq++) {
                float wq = __shfl(w, qq);
                int sq = __shfl(src, qq);
                if (lane < 40) {
                    u16x8 v = *(const u16x8*)&xb[(long)sq * STRB + lane * 8];
                    #pragma unroll
                    for (int j = 0; j < 8; j++) acc[j] += wq * b2f(v[j]);
                }
            }
        }
    }
    if (outb16) {
        if (lane < 40) {
            u16x8 o;
            #pragma unroll
            for (int j = 0; j < 8; j++) o[j] = f2b(fmaxf(acc[j], 0.f));
            *(u16x8*)&outb16[(long)node * STRB + lane * 8] = o;
        }
    } else {
        if (lane < 38) {
            #pragma unroll
            for (int j = 0; j < 8; j++) {
                int c = lane * 8 + j;
                if (c < H) outf[(long)node * out_stride + out_off + c] = fmaxf(acc[j], 0.f);
            }
        }
    }
}

// ---------------------------------------------------------------------------
// launch
// ---------------------------------------------------------------------------
extern "C" void kernel_launch(void* const* d_in, const int* in_sizes, int n_in,
                              void* d_out, int out_size, void* d_ws, size_t ws_size,
                              hipStream_t stream) {
    const float* x_e     = (const float*)d_in[0];
    const int*   ei_all  = (const int*)d_in[3];
    const float* gcn1_W  = (const float*)d_in[5];
    const float* hw1_W   = (const float*)d_in[6];
    const float* hw1_b   = (const float*)d_in[7];
    const float* gat1_ai = (const float*)d_in[8];
    const float* gat1_aj = (const float*)d_in[9];
    const float* ghw1_W  = (const float*)d_in[10];
    const float* ghw1_b  = (const float*)d_in[11];
    const float* gat2_ai = (const float*)d_in[12];
    const float* gat2_aj = (const float*)d_in[13];
    const float* ghw2_W  = (const float*)d_in[14];
    const float* ghw2_b  = (const float*)d_in[15];
    const float* gat_ai  = (const float*)d_in[16];
    const float* gat_aj  = (const float*)d_in[17];

    const int N = in_sizes[0] / H;
    const int E = in_sizes[3] / 2;
    const int* ei_j = ei_all;
    const int* ei_i = ei_all + E;

    float* out = (float*)d_out;

    size_t NSB = (size_t)N * STRB;
    u16*   W0   = (u16*)d_ws;
    u16*   W1   = W0 + NSB;
    u16*   W2   = W1 + NSB;
    u16*   W3   = W2 + NSB;
    float* G2F  = (float*)d_ws;              // spans [0, 60MB) ⊂ W0+W1 (64MB)
    float* sbi  = (float*)(W3 + NSB);
    float* sbj  = sbi + N;
    float* dinv = sbj + N;
    int*   deg  = (int*)(dinv + N);
    int*   offs = deg + N;                   // N+1
    int*   cursor = offs + (N + 1);
    int*   csr  = cursor + N;                // E ints
    int*   btot = csr + E;                   // 64
    int*   bpre = btot + 64;                 // 64
    u16*   wb0  = (u16*)(bpre + 64);         // 4 x 320x320 bf16 weights
    u16*   wb1  = wb0 + STRB * STRB;
    u16*   wb2  = wb1 + STRB * STRB;
    u16*   wb3  = wb2 + STRB * STRB;

    dim3 blk256(256);
    int rowsPerBlock = 256 / WAVE;
    dim3 gridRows((N + rowsPerBlock - 1) / rowsPerBlock);
    dim3 gridNodeW((N + 3) / 4);
    dim3 gridE(2048);
    dim3 gridW(400);
    dim3 gridGemm(((N + BM - 1) / BM) * 5);
    int nScanB = (N + SCB - 1) / SCB;

    // 1. x0b = bf16(l2_normalize(x_e)) -> W0
    hipLaunchKernelGGL(k_l2norm, gridRows, blk256, 0, stream, x_e, W0, N);

    // 2. CSR build + weight conversion
    hipLaunchKernelGGL(k_zero_int, dim3(256), blk256, 0, stream, deg, N);
    hipLaunchKernelGGL(k_count_deg, gridE, blk256, 0, stream, ei_i, deg, E);
    hipLaunchKernelGGL(k_dinv, dim3(256), blk256, 0, stream, deg, dinv, N);
    hipLaunchKernelGGL(k_scan_local, dim3(nScanB), dim3(SCB), 0, stream, deg, offs, btot, N);
    hipLaunchKernelGGL(k_scan_tots, dim3(1), dim3(64), 0, stream, btot, bpre, nScanB, offs + N);
    hipLaunchKernelGGL(k_scan_apply, dim3(256), blk256, 0, stream, offs, bpre, cursor, N);
    hipLaunchKernelGGL(k_fill_csr, gridE, blk256, 0, stream, ei_j, ei_i, cursor, csr, E);
    hipLaunchKernelGGL(k_conv_w4, gridW, blk256, 0, stream,
                       gcn1_W, hw1_W, ghw1_W, ghw2_W, wb0, wb1, wb2, wb3);

    // 3. hb = bf16(x0 @ gcn1_W.T) -> W1
    hipLaunchKernelGGL(k_gemm_fused, gridGemm, blk256, 0, stream,
                       W0, wb0, W1,
                       (const float*)nullptr, (const u16*)nullptr, (const float*)nullptr,
                       (const u16*)nullptr, (float*)nullptr, (long)0, (u16*)nullptr, N);

    // 4. gcnb -> W2
    hipLaunchKernelGGL(k_gcn_gather_w, gridNodeW, blk256, 0, stream, W1, dinv, offs, csr, W2, N);

    // 5. x2b = hw(x0b, gcnb) fused: pre = x0b@hw1_W.T -> mirror W3
    hipLaunchKernelGGL(k_gemm_fused, gridGemm, blk256, 0, stream,
                       W0, wb1, (u16*)nullptr,
                       hw1_b, W2, (const float*)nullptr, W0,
                       (float*)nullptr, (long)0, W3, N);

    // 6. dots for GAT1 from x2b
    hipLaunchKernelGGL(k_dual_dot_b, gridRows, blk256, 0, stream, W3, gat1_ai, gat1_aj, sbi, sbj, N);

    // 7. GAT1 gather on x2b -> g1b (W1)
    hipLaunchKernelGGL(k_gat_gather_w, gridNodeW, blk256, 0, stream, W3, sbi, sbj, offs, csr,
                       W1, (float*)nullptr, (long)0, 0, N);

    // 8. x3b = hw(x2b, g1b) fused: pre = x2b@ghw1_W.T -> mirror W2
    hipLaunchKernelGGL(k_gemm_fused, gridGemm, blk256, 0, stream,
                       W3, wb2, (u16*)nullptr,
                       ghw1_b, W1, (const float*)nullptr, W3,
                       (float*)nullptr, (long)0, W2, N);

    // 9. dots for GAT2 from x3b
    hipLaunchKernelGGL(k_dual_dot_b, gridRows, blk256, 0, stream, W2, gat2_ai, gat2_aj, sbi, sbj, N);

    // 10. GAT2 gather on x3b -> G2F (fp32, contiguous stride H)
    hipLaunchKernelGGL(k_gat_gather_w, gridNodeW, blk256, 0, stream, W2, sbi, sbj, offs, csr,
                       (u16*)nullptr, G2F, (long)H, 0, N);

    // 11. xe = hw(x2b, G2F) fused: pre = x2b@ghw2_W.T -> d_out[:,0:300] fp32 + mirror xeb (W2)
    hipLaunchKernelGGL(k_gemm_fused, gridGemm, blk256, 0, stream,
                       W3, wb3, (u16*)nullptr,
                       ghw2_b, (const u16*)nullptr, G2F, W3,
                       out, (long)(2 * H), W2, N);

    // 12. dots for final GAT from xeb
    hipLaunchKernelGGL(k_dual_dot_b, gridRows, blk256, 0, stream, W2, gat_ai, gat_aj, sbi, sbj, N);

    // 13. final GAT gather on xeb -> d_out[:,300:600]
    hipLaunchKernelGGL(k_gat_gather_w, gridNodeW, blk256, 0, stream, W2, sbi, sbj, offs, csr,
                       (u16*)nullptr, out, (long)(2 * H), H, N);
}

// Round 12
// 693.017 us; speedup vs baseline: 1.4900x; 1.0730x over previous
//
#include <hip/hip_runtime.h>
#include <hip/hip_bf16.h>
#include <math.h>

#define H 300
#define WAVE 64
#define STRB 320   // padded bf16 row stride (640 B; 40 chunks of 16 B)
#define SCB 1024

typedef short bf16x8 __attribute__((ext_vector_type(8)));
typedef unsigned short u16;
typedef u16 u16x8 __attribute__((ext_vector_type(8)));
typedef u16 u16x4 __attribute__((ext_vector_type(4)));
typedef float f32x4 __attribute__((ext_vector_type(4)));

__device__ inline unsigned short f2b(float f) {
    union { float f; unsigned int u; } x; x.f = f;
    unsigned int r = x.u + 0x7FFF + ((x.u >> 16) & 1);
    return (unsigned short)(r >> 16);
}
__device__ inline float b2f(u16 h) {
    union { float f; unsigned int u; } x; x.u = ((unsigned int)h) << 16;
    return x.f;
}

// ---------------------------------------------------------------------------
// l2 normalize rows: one wave per row; bf16 padded output only
// ---------------------------------------------------------------------------
__global__ void k_l2norm(const float* __restrict__ x, u16* __restrict__ outb, int n) {
    int wave = blockIdx.x * (blockDim.x / WAVE) + (threadIdx.x >> 6);
    int lane = threadIdx.x & 63;
    if (wave >= n) return;
    const float* row = x + (long)wave * H;
    float s = 0.f;
    for (int j = lane; j < H; j += WAVE) { float v = row[j]; s += v * v; }
    for (int o = 32; o > 0; o >>= 1) s += __shfl_xor(s, o);
    float sc = 1.0f / fmaxf(sqrtf(s), 1e-12f);
    u16* brow = outb + (long)wave * STRB;
    for (int j = lane; j < H; j += WAVE) brow[j] = f2b(row[j] * sc);
    for (int j = H + lane; j < STRB; j += WAVE) brow[j] = 0;
}

__global__ void k_zero_int(int* p, int n) {
    int i = blockIdx.x * blockDim.x + threadIdx.x;
    int stride = gridDim.x * blockDim.x;
    for (; i < n; i += stride) p[i] = 0;
}

__global__ void k_count_deg(const int* __restrict__ ei_i, int* __restrict__ deg, int E) {
    int i = blockIdx.x * blockDim.x + threadIdx.x;
    int stride = gridDim.x * blockDim.x;
    for (; i < E; i += stride) atomicAdd(&deg[ei_i[i]], 1);
}

// ---------------------------------------------------------------------------
// parallel exclusive scan of deg -> offs(+cursor), offs[n]=total; dinv fused
// ---------------------------------------------------------------------------
__global__ void k_scan_local(const int* __restrict__ deg, int* __restrict__ offs,
                             int* __restrict__ btot, float* __restrict__ dinv, int n) {
    __shared__ int sh[SCB];
    int base = blockIdx.x * SCB;
    int tid = threadIdx.x;
    int v = (base + tid < n) ? deg[base + tid] : 0;
    if (base + tid < n) dinv[base + tid] = (v > 0) ? 1.0f / sqrtf((float)v) : 0.0f;
    sh[tid] = v;
    __syncthreads();
    for (int off = 1; off < SCB; off <<= 1) {
        int add = (tid >= off) ? sh[tid - off] : 0;
        __syncthreads();
        sh[tid] += add;
        __syncthreads();
    }
    if (base + tid < n) offs[base + tid] = sh[tid] - v;
    if (tid == SCB - 1) btot[blockIdx.x] = sh[tid];
}

__global__ void k_scan_tots(const int* __restrict__ btot, int* __restrict__ bpre,
                            int nb, int* __restrict__ total_out) {
    int l = threadIdx.x;   // single wave of 64; nb <= 64
    int v = (l < nb) ? btot[l] : 0;
    int own = v;
    for (int o = 1; o < 64; o <<= 1) {
        int u = __shfl_up(v, o);
        if (l >= o) v += u;
    }
    if (l < nb) bpre[l] = v - own;
    if (l == 63) total_out[0] = v;
}

__global__ void k_scan_apply(int* __restrict__ offs, const int* __restrict__ bpre,
                             int* __restrict__ cursor, int n) {
    int i = blockIdx.x * blockDim.x + threadIdx.x;
    int stride = gridDim.x * blockDim.x;
    for (; i < n; i += stride) {
        int o = offs[i] + bpre[i / SCB];
        offs[i] = o;
        cursor[i] = o;
    }
}

__global__ void k_fill_csr(const int* __restrict__ ei_j, const int* __restrict__ ei_i,
                           int* __restrict__ cursor, int* __restrict__ csr_src, int E) {
    int i = blockIdx.x * blockDim.x + threadIdx.x;
    int stride = gridDim.x * blockDim.x;
    for (; i < E; i += stride) {
        int dst = ei_i[i];
        int pos = atomicAdd(&cursor[dst], 1);
        csr_src[pos] = ei_j[i];
    }
}

// ---------------------------------------------------------------------------
// 4x W fp32 [300][300] -> padded bf16 [320][320], pads zero. One launch.
// ---------------------------------------------------------------------------
__global__ void k_conv_w4(const float* __restrict__ W0f, const float* __restrict__ W1f,
                          const float* __restrict__ W2f, const float* __restrict__ W3f,
                          u16* __restrict__ Wb0, u16* __restrict__ Wb1,
                          u16* __restrict__ Wb2, u16* __restrict__ Wb3) {
    int which = blockIdx.x & 3;
    const float* W = (which == 0) ? W0f : (which == 1) ? W1f : (which == 2) ? W2f : W3f;
    u16* Wb = (which == 0) ? Wb0 : (which == 1) ? Wb1 : (which == 2) ? Wb2 : Wb3;
    int idx = (blockIdx.x >> 2) * blockDim.x + threadIdx.x;
    int stride = (gridDim.x >> 2) * blockDim.x;
    for (; idx < STRB * STRB; idx += stride) {
        int r = idx / STRB, c = idx - r * STRB;
        Wb[idx] = (r < H && c < H) ? f2b(W[r * H + c]) : 0;
    }
}

// ---------------------------------------------------------------------------
// MFMA NT GEMM, BM=128 x BN=64, 1-D grid bn-fast + bijective XCD swizzle.
// Epilogue: acc -> bf16 LDS tile [128][70] -> row-major vectorized I/O.
// mode A (outb != null): bf16 rows stride STRB (pads zeroed)
// mode B: highway: g = sigmoid(pre + bias); val = g*xnew + (1-g)*xold
// ---------------------------------------------------------------------------
#define BM 128
#define BN 64
#define BK 32
#define LDP 40
#define STP 70   // epilogue staging stride (u16)
#define NXCD 8

__global__ __launch_bounds__(256) void k_gemm_fused(
        const u16* __restrict__ Xb,
        const u16* __restrict__ Wb,
        u16* __restrict__ outb,
        const float* __restrict__ hwbias,
        const u16* __restrict__ xnewb, const float* __restrict__ xnewf,
        const u16* __restrict__ xold,
        float* __restrict__ outf, long ostride,
        u16* __restrict__ mirror,
        int n_rows) {
    __shared__ __align__(16) char smem[BM * STP * 2];   // 17920 B
    short* As = (short*)smem;                           // [BM][LDP]
    short* Bs = (short*)(smem + BM * LDP * 2);          // [BN][LDP]
    u16*   St = (u16*)smem;                             // [BM][STP] (epilogue)
    const int tid = threadIdx.x;

    const int nwg = gridDim.x;
    const int q = nwg / NXCD, r = nwg % NXCD;
    const int xcd = blockIdx.x % NXCD, idx = blockIdx.x / NXCD;
    const int wgid = (xcd < r ? xcd * (q + 1) : r * (q + 1) + (xcd - r) * q) + idx;
    const int bm = (wgid / 5) * BM;
    const int bn = (wgid % 5) * BN;

    const int lane = tid & 63;
    const int wid = tid >> 6;
    const int wr = wid >> 1;
    const int wc = wid & 1;
    const int lrow = lane & 15;
    const int kgrp = lane >> 4;

    f32x4 acc[4][2];
    #pragma unroll
    for (int m = 0; m < 4; m++)
        #pragma unroll
        for (int n = 0; n < 2; n++) acc[m][n] = (f32x4){0.f, 0.f, 0.f, 0.f};

    for (int k0 = 0; k0 < STRB; k0 += BK) {
        #pragma unroll
        for (int i = 0; i < 2; ++i) {
            int qq = tid + i * 256;
            int rr = qq >> 2, c = (qq & 3) << 3;
            int gr = bm + rr;
            u16x8 v = {0, 0, 0, 0, 0, 0, 0, 0};
            if (gr < n_rows) v = *(const u16x8*)&Xb[(long)gr * STRB + k0 + c];
            *(u16x8*)&As[rr * LDP + c] = v;
        }
        {
            int rr = tid >> 2, c = (tid & 3) << 3;
            u16x8 v = *(const u16x8*)&Wb[(long)(bn + rr) * STRB + k0 + c];
            *(u16x8*)&Bs[rr * LDP + c] = v;
        }
        __syncthreads();

        bf16x8 af[4], bfr[2];
        #pragma unroll
        for (int m = 0; m < 4; m++) {
            int row = wr * 64 + m * 16 + lrow;
            af[m] = *(const bf16x8*)&As[row * LDP + kgrp * 8];
        }
        #pragma unroll
        for (int n = 0; n < 2; n++) {
            int col = wc * 32 + n * 16 + lrow;
            bfr[n] = *(const bf16x8*)&Bs[col * LDP + kgrp * 8];
        }
        #pragma unroll
        for (int m = 0; m < 4; m++)
            #pragma unroll
            for (int n = 0; n < 2; n++)
                acc[m][n] = __builtin_amdgcn_mfma_f32_16x16x32_bf16(af[m], bfr[n], acc[m][n], 0, 0, 0);
        __syncthreads();
    }

    // stage acc (bf16) into LDS tile [128][STP]
    #pragma unroll
    for (int m = 0; m < 4; m++)
        #pragma unroll
        for (int n = 0; n < 2; n++) {
            int lc = wc * 32 + n * 16 + lrow;
            #pragma unroll
            for (int rr = 0; rr < 4; rr++) {
                int row = wr * 64 + m * 16 + kgrp * 4 + rr;
                St[row * STP + lc] = f2b(acc[m][n][rr]);
            }
        }
    __syncthreads();

    // vectorized epilogue: 8 threads/row, 4 passes of 32 rows
    #pragma unroll
    for (int p = 0; p < 4; p++) {
        int row = p * 32 + (tid >> 3);
        int gr = bm + row;
        if (gr >= n_rows) continue;
        int lc0 = (tid & 7) * 8;
        int gc0 = bn + lc0;
        u16x8 pv = *(const u16x8*)&St[row * STP + lc0];
        if (outb) {
            u16x8 o;
            #pragma unroll
            for (int j = 0; j < 8; j++) o[j] = (gc0 + j < H) ? pv[j] : (u16)0;
            *(u16x8*)&outb[(long)gr * STRB + gc0] = o;
        } else {
            u16x8 xov = *(const u16x8*)&xold[(long)gr * STRB + gc0];
            float xn[8];
            if (xnewb) {
                u16x8 xnv = *(const u16x8*)&xnewb[(long)gr * STRB + gc0];
                #pragma unroll
                for (int j = 0; j < 8; j++) xn[j] = b2f(xnv[j]);
            } else {
                f32x4 a = *(const f32x4*)&xnewf[(long)gr * H + gc0];
                f32x4 b = *(const f32x4*)&xnewf[(long)gr * H + gc0 + 4];
                xn[0] = a[0]; xn[1] = a[1]; xn[2] = a[2]; xn[3] = a[3];
                xn[4] = b[0]; xn[5] = b[1]; xn[6] = b[2]; xn[7] = b[3];
            }
            float val[8];
            #pragma unroll
            for (int j = 0; j < 8; j++) {
                int gcj = gc0 + j;
                if (gcj < H) {
                    float pre = b2f(pv[j]) + hwbias[gcj];
                    float g = 1.0f / (1.0f + __expf(-pre));
                    val[j] = g * xn[j] + (1.0f - g) * b2f(xov[j]);
                } else val[j] = 0.f;
            }
            if (outf) {
                if (gc0 < H)
                    *(f32x4*)&outf[(long)gr * ostride + gc0] = (f32x4){val[0], val[1], val[2], val[3]};
                if (gc0 + 4 < H)
                    *(f32x4*)&outf[(long)gr * ostride + gc0 + 4] = (f32x4){val[4], val[5], val[6], val[7]};
            }
            if (mirror) {
                u16x8 mv;
                #pragma unroll
                for (int j = 0; j < 8; j++) mv[j] = f2b(val[j]);
                *(u16x8*)&mirror[(long)gr * STRB + gc0] = mv;
            }
        }
    }
}

// ---------------------------------------------------------------------------
// GCN gather, wave-per-node: lane<40 owns one u16x8 chunk across all edges.
// ---------------------------------------------------------------------------
__global__ __launch_bounds__(256) void k_gcn_gather_w(const u16* __restrict__ xb,
                                                      const float* __restrict__ dinv,
                                                      const int* __restrict__ offs,
                                                      const int* __restrict__ csr,
                                                      u16* __restrict__ outb, int n) {
    int node = blockIdx.x * 4 + (threadIdx.x >> 6);
    int lane = threadIdx.x & 63;
    if (node >= n) return;
    int start = offs[node], end = offs[node + 1];
    float acc[8];
    #pragma unroll
    for (int j = 0; j < 8; j++) acc[j] = 0.f;
    float di = dinv[node];
    for (int tb = start; tb < end; tb += 64) {
        int p = tb + lane;
        int src = 0; float w = 0.f;
        if (p < end) {
            src = csr[p];
            w = di * dinv[src];
        }
        int cnt = min(64, end - tb);
        for (int qq = 0; qq < cnt; qq++) {
            float wq = __shfl(w, qq);
            int sq = __shfl(src, qq);
            if (lane < 40) {
                u16x8 v = *(const u16x8*)&xb[(long)sq * STRB + lane * 8];
                #pragma unroll
                for (int j = 0; j < 8; j++) acc[j] += wq * b2f(v[j]);
            }
        }
    }
    if (lane < 40) {
        u16x8 o;
        #pragma unroll
        for (int j = 0; j < 8; j++) o[j] = f2b(fmaxf(acc[j], 0.f));
        *(u16x8*)&outb[(long)node * STRB + lane * 8] = o;
    }
}

// ---------------------------------------------------------------------------
// dual dot from bf16 mirror: one wave per row
// ---------------------------------------------------------------------------
__global__ void k_dual_dot_b(const u16* __restrict__ xb,
                             const float* __restrict__ ai, const float* __restrict__ aj,
                             float* __restrict__ s_i, float* __restrict__ s_j, int n) {
    int wave = blockIdx.x * (blockDim.x / WAVE) + (threadIdx.x >> 6);
    int lane = threadIdx.x & 63;
    if (wave >= n) return;
    const u16* row = xb + (long)wave * STRB;
    float d0 = 0.f, d1 = 0.f;
    {
        u16x4 v = *(const u16x4*)&row[lane * 4];
        float4 a4 = *(const float4*)&ai[lane * 4];
        float4 j4 = *(const float4*)&aj[lane * 4];
        float x0 = b2f(v[0]), x1 = b2f(v[1]), x2 = b2f(v[2]), x3 = b2f(v[3]);
        d0 = x0 * a4.x + x1 * a4.y + x2 * a4.z + x3 * a4.w;
        d1 = x0 * j4.x + x1 * j4.y + x2 * j4.z + x3 * j4.w;
    }
    if (lane < 11) {
        u16x4 v = *(const u16x4*)&row[256 + lane * 4];
        float4 a4 = *(const float4*)&ai[256 + lane * 4];
        float4 j4 = *(const float4*)&aj[256 + lane * 4];
        float x0 = b2f(v[0]), x1 = b2f(v[1]), x2 = b2f(v[2]), x3 = b2f(v[3]);
        d0 += x0 * a4.x + x1 * a4.y + x2 * a4.z + x3 * a4.w;
        d1 += x0 * j4.x + x1 * j4.y + x2 * j4.z + x3 * j4.w;
    }
    for (int o = 32; o > 0; o >>= 1) { d0 += __shfl_down(d0, o); d1 += __shfl_down(d1, o); }
    if (lane == 0) { s_i[wave] = d0; s_j[wave] = d1; }
}

// ---------------------------------------------------------------------------
// GAT gather, wave-per-node, fused softmax (two-pass, tiles of 64).
// ---------------------------------------------------------------------------
__global__ __launch_bounds__(256) void k_gat_gather_w(const u16* __restrict__ xb,
                                                      const float* __restrict__ s_i_arr,
                                                      const float* __restrict__ s_j_arr,
                                                      const int* __restrict__ offs,
                                                      const int* __restrict__ csr,
                                                      u16* __restrict__ outb16,
                                                      float* __restrict__ outf, long out_stride,
                                                      int out_off, int n) {
    int node = blockIdx.x * 4 + (threadIdx.x >> 6);
    int lane = threadIdx.x & 63;
    if (node >= n) return;
    int start = offs[node], end = offs[node + 1];
    int deg = end - start;
    float acc[8];
    #pragma unroll
    for (int j = 0; j < 8; j++) acc[j] = 0.f;

    if (deg > 0) {
        float si = s_i_arr[node];
        float m_t = -1e30f, s_t = 0.f;
        for (int p = start + lane; p < end; p += 64) {
            float sc = si + s_j_arr[csr[p]];
            sc = (sc >= 0.f) ? sc : 0.01f * sc;
            if (sc > m_t) { s_t = s_t * __expf(m_t - sc) + 1.0f; m_t = sc; }
            else s_t += __expf(sc - m_t);
        }
        for (int o = 32; o > 0; o >>= 1) {
            float m2 = __shfl_xor(m_t, o), s2 = __shfl_xor(s_t, o);
            float mm = fmaxf(m_t, m2);
            s_t = s_t * __expf(m_t - mm) + s2 * __expf(m2 - mm);
            m_t = mm;
        }
        float m = m_t;
        float inv = 1.0f / (s_t + 1e-16f);
        for (int tb = start; tb < end; tb += 64) {
            int p = tb + lane;
            int src = 0; float w = 0.f;
            if (p < end) {
                src = csr[p];
                float sc = si + s_j_arr[src];
                sc = (sc >= 0.f) ? sc : 0.01f * sc;
                w = __expf(sc - m) * inv;
            }
            int cnt = min(64, end - tb);
            for (int qq = 0; qq < cnt; qq++) {
                float wq = __shfl(w, qq);
                int sq = __shfl(src, qq);
                if (lane < 40) {
                    u16x8 v = *(const u16x8*)&xb[(long)sq * STRB + lane * 8];
                    #pragma unroll
                    for (int j = 0; j < 8; j++) acc[j] += wq * b2f(v[j]);
                }
            }
        }
    }
    if (outb16) {
        if (lane < 40) {
            u16x8 o;
            #pragma unroll
            for (int j = 0; j < 8; j++) o[j] = f2b(fmaxf(acc[j], 0.f));
            *(u16x8*)&outb16[(long)node * STRB + lane * 8] = o;
        }
    } else {
        if (lane < 38) {
            #pragma unroll
            for (int j = 0; j < 8; j++) {
                int c = lane * 8 + j;
                if (c < H) outf[(long)node * out_stride + out_off + c] = fmaxf(acc[j], 0.f);
            }
        }
    }
}

// ---------------------------------------------------------------------------
// launch
// ---------------------------------------------------------------------------
extern "C" void kernel_launch(void* const* d_in, const int* in_sizes, int n_in,
                              void* d_out, int out_size, void* d_ws, size_t ws_size,
                              hipStream_t stream) {
    const float* x_e     = (const float*)d_in[0];
    const int*   ei_all  = (const int*)d_in[3];
    const float* gcn1_W  = (const float*)d_in[5];
    const float* hw1_W   = (const float*)d_in[6];
    const float* hw1_b   = (const float*)d_in[7];
    const float* gat1_ai = (const float*)d_in[8];
    const float* gat1_aj = (const float*)d_in[9];
    const float* ghw1_W  = (const float*)d_in[10];
    const float* ghw1_b  = (const float*)d_in[11];
    const float* gat2_ai = (const float*)d_in[12];
    const float* gat2_aj = (const float*)d_in[13];
    const float* ghw2_W  = (const float*)d_in[14];
    const float* ghw2_b  = (const float*)d_in[15];
    const float* gat_ai  = (const float*)d_in[16];
    const float* gat_aj  = (const float*)d_in[17];

    const int N = in_sizes[0] / H;
    const int E = in_sizes[3] / 2;
    const int* ei_j = ei_all;
    const int* ei_i = ei_all + E;

    float* out = (float*)d_out;

    size_t NSB = (size_t)N * STRB;
    u16*   W0   = (u16*)d_ws;
    u16*   W1   = W0 + NSB;
    u16*   W2   = W1 + NSB;
    u16*   W3   = W2 + NSB;
    float* G2F  = (float*)d_ws;              // spans [0, 60MB) ⊂ W0+W1 (64MB)
    float* sbi  = (float*)(W3 + NSB);
    float* sbj  = sbi + N;
    float* dinv = sbj + N;
    int*   deg  = (int*)(dinv + N);
    int*   offs = deg + N;                   // N+1
    int*   cursor = offs + (N + 1);
    int*   csr  = cursor + N;                // E ints
    int*   btot = csr + E;                   // 64
    int*   bpre = btot + 64;                 // 64
    u16*   wb0  = (u16*)(bpre + 64);         // 4 x 320x320 bf16 weights
    u16*   wb1  = wb0 + STRB * STRB;
    u16*   wb2  = wb1 + STRB * STRB;
    u16*   wb3  = wb2 + STRB * STRB;

    dim3 blk256(256);
    int rowsPerBlock = 256 / WAVE;
    dim3 gridRows((N + rowsPerBlock - 1) / rowsPerBlock);
    dim3 gridNodeW((N + 3) / 4);
    dim3 gridE(2048);
    dim3 gridW(400);
    dim3 gridGemm(((N + BM - 1) / BM) * 5);
    int nScanB = (N + SCB - 1) / SCB;

    // 1. x0b = bf16(l2_normalize(x_e)) -> W0
    hipLaunchKernelGGL(k_l2norm, gridRows, blk256, 0, stream, x_e, W0, N);

    // 2. CSR build + weight conversion
    hipLaunchKernelGGL(k_zero_int, dim3(256), blk256, 0, stream, deg, N);
    hipLaunchKernelGGL(k_count_deg, gridE, blk256, 0, stream, ei_i, deg, E);
    hipLaunchKernelGGL(k_scan_local, dim3(nScanB), dim3(SCB), 0, stream, deg, offs, btot, dinv, N);
    hipLaunchKernelGGL(k_scan_tots, dim3(1), dim3(64), 0, stream, btot, bpre, nScanB, offs + N);
    hipLaunchKernelGGL(k_scan_apply, dim3(256), blk256, 0, stream, offs, bpre, cursor, N);
    hipLaunchKernelGGL(k_fill_csr, gridE, blk256, 0, stream, ei_j, ei_i, cursor, csr, E);
    hipLaunchKernelGGL(k_conv_w4, gridW, blk256, 0, stream,
                       gcn1_W, hw1_W, ghw1_W, ghw2_W, wb0, wb1, wb2, wb3);

    // 3. hb = bf16(x0 @ gcn1_W.T) -> W1
    hipLaunchKernelGGL(k_gemm_fused, gridGemm, blk256, 0, stream,
                       W0, wb0, W1,
                       (const float*)nullptr, (const u16*)nullptr, (const float*)nullptr,
                       (const u16*)nullptr, (float*)nullptr, (long)0, (u16*)nullptr, N);

    // 4. gcnb -> W2
    hipLaunchKernelGGL(k_gcn_gather_w, gridNodeW, blk256, 0, stream, W1, dinv, offs, csr, W2, N);

    // 5. x2b = hw(x0b, gcnb) fused: pre = x0b@hw1_W.T -> mirror W3
    hipLaunchKernelGGL(k_gemm_fused, gridGemm, blk256, 0, stream,
                       W0, wb1, (u16*)nullptr,
                       hw1_b, W2, (const float*)nullptr, W0,
                       (float*)nullptr, (long)0, W3, N);

    // 6. dots for GAT1 from x2b
    hipLaunchKernelGGL(k_dual_dot_b, gridRows, blk256, 0, stream, W3, gat1_ai, gat1_aj, sbi, sbj, N);

    // 7. GAT1 gather on x2b -> g1b (W1)
    hipLaunchKernelGGL(k_gat_gather_w, gridNodeW, blk256, 0, stream, W3, sbi, sbj, offs, csr,
                       W1, (float*)nullptr, (long)0, 0, N);

    // 8. x3b = hw(x2b, g1b) fused: pre = x2b@ghw1_W.T -> mirror W2
    hipLaunchKernelGGL(k_gemm_fused, gridGemm, blk256, 0, stream,
                       W3, wb2, (u16*)nullptr,
                       ghw1_b, W1, (const float*)nullptr, W3,
                       (float*)nullptr, (long)0, W2, N);

    // 9. dots for GAT2 from x3b
    hipLaunchKernelGGL(k_dual_dot_b, gridRows, blk256, 0, stream, W2, gat2_ai, gat2_aj, sbi, sbj, N);

    // 10. GAT2 gather on x3b -> G2F (fp32, contiguous stride H)
    hipLaunchKernelGGL(k_gat_gather_w, gridNodeW, blk256, 0, stream, W2, sbi, sbj, offs, csr,
                       (u16*)nullptr, G2F, (long)H, 0, N);

    // 11. xe = hw(x2b, G2F) fused: pre = x2b@ghw2_W.T -> d_out[:,0:300] fp32 + mirror xeb (W2)
    hipLaunchKernelGGL(k_gemm_fused, gridGemm, blk256, 0, stream,
                       W3, wb3, (u16*)nullptr,
                       ghw2_b, (const u16*)nullptr, G2F, W3,
                       out, (long)(2 * H), W2, N);

    // 12. dots for final GAT from xeb
    hipLaunchKernelGGL(k_dual_dot_b, gridRows, blk256, 0, stream, W2, gat_ai, gat_aj, sbi, sbj, N);

    // 13. final GAT gather on xeb -> d_out[:,300:600]
    hipLaunchKernelGGL(k_gat_gather_w, gridNodeW, blk256, 0, stream, W2, sbi, sbj, offs, csr,
                       (u16*)nullptr, out, (long)(2 * H), H, N);
}